// Round 1
// baseline (658.450 us; speedup 1.0000x reference)
//
#include <hip/hip_runtime.h>
#include <hip/hip_bf16.h>

#define B_ 32
#define N_ 8192
#define DI_ 128
#define D_ 512
#define NC_ 1000
#define TN_ 128          // items per output tile (per block)
#define SN_ 64           // items per sub-tile (LDS working set); 2 sub-tiles/block
#define NT_ 64           // tiles = N_/TN_
#define LROW_ 520        // h1s row stride in shorts (pad +8)
#define XROW_ 136        // x_lds row stride in shorts (pad +8)

typedef short s8v __attribute__((ext_vector_type(8)));
typedef float f4v __attribute__((ext_vector_type(4)));

__device__ __forceinline__ unsigned short f2bf(float f){
  union { float f; unsigned u; } c; c.f = f;
  unsigned r = c.u + 0x7fffu + ((c.u >> 16) & 1u);
  return (unsigned short)(r >> 16);
}

// hardware v_cvt_pk_bf16_f32: 2 floats -> packed bf16 (RNE), a in low 16
__device__ __forceinline__ unsigned pk2bf(float a, float b){
  float2 f; f.x = a; f.y = b;
  __hip_bfloat162 h = __float22bfloat162_rn(f);
  union { __hip_bfloat162 h; unsigned u; } c; c.h = h;
  return c.u;
}

// exact GELU: 0.5x(1+erf(x/sqrt2)); Abramowitz-Stegun 7.1.26, |err| <= 1.5e-7
__device__ __forceinline__ float gelu_f(float x){
  float ax = fabsf(x) * 0.70710678118654752f;
  float t = __builtin_amdgcn_rcpf(1.0f + 0.3275911f * ax);
  float poly = ((((1.061405429f*t - 1.453152027f)*t + 1.421413741f)*t
                 - 0.284496736f)*t + 0.254829592f)*t;
  float e = __expf(-ax*ax);
  float erf_ax = 1.0f - poly*e;
  erf_ax = (x >= 0.0f) ? erf_ax : -erf_ax;
  return 0.5f * x * (1.0f + erf_ax);
}

__device__ __forceinline__ float wsum64(float v){
  #pragma unroll
  for (int off = 32; off; off >>= 1) v += __shfl_xor(v, off, 64);
  return v;
}

// ---------------- prep: convert psi_x weights to bf16 in MFMA fragment order ----------------
__global__ void k_prep(const float* __restrict__ w1, const float* __restrict__ w2,
                       unsigned short* __restrict__ w1p, unsigned short* __restrict__ w2p){
  int i = blockIdx.x * 256 + threadIdx.x;
  if (i < D_*DI_){
    int j = i / DI_, kc = i % DI_;
    int kk = kc >> 5, q = (kc >> 3) & 3, s = kc & 7;
    w1p[((kk*D_ + j)*4 + q)*8 + s] = f2bf(w1[i]);
  }
  if (i < D_*D_){
    int j = i / D_, kc = i % D_;
    int kk = kc >> 5, q = (kc >> 3) & 3, s = kc & 7;
    w2p[((kk*D_ + j)*4 + q)*8 + s] = f2bf(w2[i]);
  }
}

// ---------------- query path, wide: grid (32, 8) x 64 ----------------
__global__ __launch_bounds__(64)
void k_q2(const float* __restrict__ xq,
          const float* __restrict__ w1q, const float* __restrict__ b1q,
          const float* __restrict__ w2q, const float* __restrict__ b2q,
          float* __restrict__ h2g){
  const int b = blockIdx.x, sl = blockIdx.y, t = threadIdx.x;
  __shared__ float h1[D_];
  const float xv = xq[b];
  #pragma unroll
  for (int i = 0; i < 8; ++i){
    int j = i*64 + t;
    h1[j] = gelu_f(xv * w1q[j] + b1q[j]);
  }
  __syncthreads();
  const int d = sl*64 + t;
  const float4* rw = (const float4*)(w2q + (size_t)d*D_);
  float a = 0.f;
  for (int kk = 0; kk < 128; ++kk){
    float4 hv = *(const float4*)&h1[kk*4];
    float4 wv = rw[kk];
    a += wv.x*hv.x + wv.y*hv.y + wv.z*hv.z + wv.w*hv.w;
  }
  h2g[b*D_ + d] = a + b2q[d];
}

__global__ __launch_bounds__(64)
void k_q3(const float* __restrict__ h2g,
          const float* __restrict__ qw, const float* __restrict__ qb,
          float* __restrict__ qvg){
  const int b = blockIdx.x, sl = blockIdx.y, t = threadIdx.x;
  __shared__ float h2[D_];
  #pragma unroll
  for (int i = 0; i < 8; ++i) h2[i*64 + t] = h2g[b*D_ + i*64 + t];
  __syncthreads();
  const int d = sl*64 + t;
  const float4* rw = (const float4*)(qw + (size_t)d*D_);
  float a = 0.f;
  for (int kk = 0; kk < 128; ++kk){
    float4 hv = *(const float4*)&h2[kk*4];
    float4 wv = rw[kk];
    a += wv.x*hv.x + wv.y*hv.y + wv.z*hv.z + wv.w*hv.w;
  }
  qvg[b*D_ + d] = a + qb[d];
}

__global__ __launch_bounds__(64)
void k_q4(const float* __restrict__ qvg, const float* __restrict__ kw,
          float* __restrict__ qk_out){
  const int b = blockIdx.x, sl = blockIdx.y, t = threadIdx.x;
  __shared__ float qv[D_];
  #pragma unroll
  for (int i = 0; i < 8; ++i) qv[i*64 + t] = qvg[b*D_ + i*64 + t];
  __syncthreads();
  const int d = sl*64 + t;
  float c0 = 0.f;
  for (int j = 0; j < D_; ++j) c0 += qv[j] * kw[(size_t)j*D_ + d];
  qk_out[b*D_ + d] = 0.04419417382415922f * c0;  // 512^-0.5
}

// ---------------- main: 128 items/block as 2x64 sub-tiles, 512 thr (8 waves) ----------------
// LDS = 68,864 B -> 2 blocks/CU (16 waves/CU, 4 waves/SIMD); regs capped to 128 via
// __launch_bounds__(512,4). One block computes while the other sits in barrier drain.
__global__ __launch_bounds__(512, 4)
void k_main(const float* __restrict__ x,                 // [B,N,DI]
            const unsigned short* __restrict__ w1p,      // packed bf16
            const float* __restrict__ b1,
            const unsigned short* __restrict__ w2p,      // packed bf16
            const float* __restrict__ b2,
            const float* __restrict__ qk,                // [B,D]
            float* __restrict__ part,                    // [B,NT,D]
            float* __restrict__ esum){                   // [B,NT]
  const int tile = blockIdx.x;       // 0..63
  const int b = blockIdx.y;          // 0..31
  const int t = threadIdx.x;         // 0..511
  const int lane = t & 63;
  const int wid = t >> 6;            // 0..7
  const int ln = lane & 15;
  const int q  = lane >> 4;          // 0..3

  __shared__ unsigned short h1s[SN_ * LROW_];   // 66,560 B; low part aliased as x_lds
  __shared__ float s_ws[8][SN_];                // 2,048 B
  __shared__ float e_lds[SN_];                  // 256 B

  const int jb = wid * 64;              // this wave's 64-col j block
  const unsigned short* w1base = w1p + (jb + ln)*32 + q*8;
  const unsigned short* w2base = w2p + (jb + ln)*32 + q*8;

  // loop-invariant per-wave constants
  float b2v[4], qkv[4];
  #pragma unroll
  for (int ni = 0; ni < 4; ++ni){
    const int j2 = jb + ni*16 + ln;
    b2v[ni] = b2[j2];
    qkv[ni] = qk[b*D_ + j2];
  }

  float zacc[4] = {0.f, 0.f, 0.f, 0.f};   // e-weighted h2 partial, accumulated over sub-tiles
  float etot = 0.f;                        // valid in wave 0

  for (int sub = 0; sub < 2; ++sub){
    const int n0 = tile * TN_ + sub * SN_;

    // ---- stage x sub-tile to LDS as bf16 (x_lds aliases h1s[0..SN_*XROW_)) ----
    {
      const float4* xb4 = (const float4*)(x + ((size_t)b * N_ + n0) * DI_);
      #pragma unroll
      for (int i = 0; i < 4; ++i){
        const int f = i*512 + t;            // float4 index; 32 float4 per row, 64 rows
        float4 v = xb4[f];
        const int m = f >> 5;
        const int k = (f & 31) << 2;
        uint2 pk;
        pk.x = pk2bf(v.x, v.y);
        pk.y = pk2bf(v.z, v.w);
        *(uint2*)&h1s[m*XROW_ + k] = pk;
      }
    }
    __syncthreads();

    f4v acc[16];
    #pragma unroll
    for (int i = 0; i < 16; ++i) acc[i] = (f4v){0.f,0.f,0.f,0.f};

    // ---- GEMM1: h1^T[j,m] = sum_k w1[j,k] * x[m,k] ----
    #pragma unroll
    for (int kk = 0; kk < 4; ++kk){
      const int k = kk*32 + q*8;
      s8v aw[4];
      #pragma unroll
      for (int jt = 0; jt < 4; ++jt)
        aw[jt] = *(const s8v*)(w1base + kk*(D_*32) + jt*(16*32));
      s8v bx[4];
      #pragma unroll
      for (int mi = 0; mi < 4; ++mi)
        bx[mi] = *(const s8v*)&h1s[(mi*16 + ln)*XROW_ + k];
      #pragma unroll
      for (int jt = 0; jt < 4; ++jt)
        #pragma unroll
        for (int mi = 0; mi < 4; ++mi)
          acc[jt*4+mi] = __builtin_amdgcn_mfma_f32_16x16x32_bf16(aw[jt], bx[mi], acc[jt*4+mi], 0,0,0);
    }
    __syncthreads();   // all waves done reading x_lds before h1s overwrite

    // ---- bias + exact GELU + pack to row-major h1s[m][k] ----
    #pragma unroll
    for (int jt = 0; jt < 4; ++jt){
      const int j0 = jb + jt*16 + q*4;
      const float bv0 = b1[j0], bv1 = b1[j0+1], bv2 = b1[j0+2], bv3 = b1[j0+3];
      #pragma unroll
      for (int mi = 0; mi < 4; ++mi){
        const int m = mi*16 + ln;
        f4v v = acc[jt*4+mi];
        uint2 pk;
        pk.x = pk2bf(gelu_f(v[0]+bv0), gelu_f(v[1]+bv1));
        pk.y = pk2bf(gelu_f(v[2]+bv2), gelu_f(v[3]+bv3));
        *(uint2*)&h1s[m*LROW_ + j0] = pk;
      }
    }
    __syncthreads();

    #pragma unroll
    for (int i = 0; i < 16; ++i) acc[i] = (f4v){0.f,0.f,0.f,0.f};

    // ---- GEMM2: h2[m,j2] = sum_k h1[m,k] * w2[j2,k]; wave owns 64 j2 cols ----
    #pragma unroll 2
    for (int kk = 0; kk < 16; ++kk){
      const int k = kk*32 + q*8;
      s8v ah[4];
      #pragma unroll
      for (int mi = 0; mi < 4; ++mi)
        ah[mi] = *(const s8v*)&h1s[(mi*16 + ln)*LROW_ + k];
      s8v bw[4];
      #pragma unroll
      for (int ni = 0; ni < 4; ++ni)
        bw[ni] = *(const s8v*)(w2base + kk*(D_*32) + ni*(16*32));
      #pragma unroll
      for (int mi = 0; mi < 4; ++mi)
        #pragma unroll
        for (int ni = 0; ni < 4; ++ni)
          acc[mi*4+ni] = __builtin_amdgcn_mfma_f32_16x16x32_bf16(ah[mi], bw[ni], acc[mi*4+ni], 0,0,0);
    }

    // ---- bias + qk dot ----
    #pragma unroll
    for (int mi = 0; mi < 4; ++mi)
      #pragma unroll
      for (int ni = 0; ni < 4; ++ni)
        #pragma unroll
        for (int r = 0; r < 4; ++r)
          acc[mi*4+ni][r] += b2v[ni];

    // partial scores over this wave's 64 cols (m = mi*16 + q*4 + r, col = ln)
    #pragma unroll
    for (int mi = 0; mi < 4; ++mi){
      #pragma unroll
      for (int r = 0; r < 4; ++r){
        float sp = 0.f;
        #pragma unroll
        for (int ni = 0; ni < 4; ++ni) sp += qkv[ni] * acc[mi*4+ni][r];
        sp += __shfl_xor(sp, 1, 64);
        sp += __shfl_xor(sp, 2, 64);
        sp += __shfl_xor(sp, 4, 64);
        sp += __shfl_xor(sp, 8, 64);
        if (ln == ((mi*4 + r) & 15)) s_ws[wid][mi*16 + q*4 + r] = sp;
      }
    }
    __syncthreads();

    if (t < SN_){
      float s = 0.f;
      #pragma unroll
      for (int w = 0; w < 8; ++w) s += s_ws[w][t];
      e_lds[t] = __expf(s);   // |s| small; constant shift cancels in softmax
    }
    __syncthreads();
    if (t < 64) etot += wsum64(e_lds[t]);

    // weighted h2 partial, accumulated in registers across sub-tiles
    {
      float ev[4][4];
      #pragma unroll
      for (int mi = 0; mi < 4; ++mi)
        #pragma unroll
        for (int r = 0; r < 4; ++r)
          ev[mi][r] = e_lds[mi*16 + q*4 + r];
      #pragma unroll
      for (int ni = 0; ni < 4; ++ni){
        float zp = 0.f;
        #pragma unroll
        for (int mi = 0; mi < 4; ++mi)
          #pragma unroll
          for (int r = 0; r < 4; ++r)
            zp += ev[mi][r] * acc[mi*4+ni][r];
        zacc[ni] += zp;
      }
    }
    __syncthreads();   // e_lds consumed by all waves before next sub-tile reuses LDS
  }

  if (t == 0) esum[b*NT_ + tile] = etot;

  #pragma unroll
  for (int ni = 0; ni < 4; ++ni){
    float zp = zacc[ni];
    zp += __shfl_xor(zp, 16, 64);
    zp += __shfl_xor(zp, 32, 64);
    if (lane < 16)
      part[((size_t)(b*NT_ + tile))*D_ + jb + ni*16 + ln] = zp;
  }
}

// ---------------- final path, wide ----------------
__global__ __launch_bounds__(128)
void k_fu(const float* __restrict__ part, const float* __restrict__ esum,
          float* __restrict__ u){
  const int b = blockIdx.x, sl = blockIdx.y, t = threadIdx.x;
  float p = esum[b*NT_ + (t & 63)];
  p = wsum64(p);
  const float linv = 1.0f / p;
  const int col = sl*128 + t;
  const float* pb = part + (size_t)b*NT_*D_ + col;
  float s = 0.f;
  for (int tl = 0; tl < NT_; ++tl) s += pb[tl*D_];
  u[b*D_ + col] = s * linv;
}

__global__ __launch_bounds__(64)
void k_fz(const float* __restrict__ u, const float* __restrict__ vw,
          const float* __restrict__ vb, float* __restrict__ z){
  const int b = blockIdx.x, sl = blockIdx.y, t = threadIdx.x;
  __shared__ float su[D_];
  #pragma unroll
  for (int i = 0; i < 8; ++i) su[i*64 + t] = u[b*D_ + i*64 + t];
  __syncthreads();
  const int d = sl*64 + t;
  const float4* rw = (const float4*)(vw + (size_t)d*D_);
  float a = 0.f;
  for (int kk = 0; kk < 128; ++kk){
    float4 uv = *(const float4*)&su[kk*4];
    float4 wv = rw[kk];
    a += wv.x*uv.x + wv.y*uv.y + wv.z*uv.z + wv.w*uv.w;
  }
  z[b*D_ + d] = a + vb[d];
}

__global__ __launch_bounds__(64)
void k_fh(const float* __restrict__ z, const float* __restrict__ pw1,
          const float* __restrict__ pb1, float* __restrict__ h){
  const int b = blockIdx.x, sl = blockIdx.y, t = threadIdx.x;
  __shared__ float sz[D_];
  #pragma unroll
  for (int i = 0; i < 8; ++i) sz[i*64 + t] = z[b*D_ + i*64 + t];
  __syncthreads();
  const int d = sl*64 + t;
  const float4* rw = (const float4*)(pw1 + (size_t)d*D_);
  float a = 0.f;
  for (int kk = 0; kk < 128; ++kk){
    float4 zv = *(const float4*)&sz[kk*4];
    float4 wv = rw[kk];
    a += wv.x*zv.x + wv.y*zv.y + wv.z*zv.z + wv.w*zv.w;
  }
  h[b*D_ + d] = gelu_f(a + pb1[d]);
}

__global__ __launch_bounds__(64)
void k_fo(const float* __restrict__ h, const float* __restrict__ pw2,
          const float* __restrict__ pb2, float* __restrict__ out){
  const int b = blockIdx.x, sl = blockIdx.y, t = threadIdx.x;
  __shared__ float sh[D_];
  #pragma unroll
  for (int i = 0; i < 8; ++i) sh[i*64 + t] = h[b*D_ + i*64 + t];
  __syncthreads();
  const int c = sl*64 + t;
  if (c < NC_){
    const float4* rw = (const float4*)(pw2 + (size_t)c*D_);
    float a = 0.f;
    for (int kk = 0; kk < 128; ++kk){
      float4 hv = *(const float4*)&sh[kk*4];
      float4 wv = rw[kk];
      a += wv.x*hv.x + wv.y*hv.y + wv.z*hv.z + wv.w*hv.w;
    }
    out[(size_t)b*NC_ + c] = a + pb2[c];
  }
}

extern "C" void kernel_launch(void* const* d_in, const int* in_sizes, int n_in,
                              void* d_out, int out_size, void* d_ws, size_t ws_size,
                              hipStream_t stream) {
  (void)in_sizes; (void)n_in; (void)out_size; (void)ws_size;
  const float* x_items  = (const float*)d_in[0];
  const float* x_query  = (const float*)d_in[1];
  const float* psi_x_w1 = (const float*)d_in[2];
  const float* psi_x_b1 = (const float*)d_in[3];
  const float* psi_x_w2 = (const float*)d_in[4];
  const float* psi_x_b2 = (const float*)d_in[5];
  const float* psi_q_w1 = (const float*)d_in[6];
  const float* psi_q_b1 = (const float*)d_in[7];
  const float* psi_q_w2 = (const float*)d_in[8];
  const float* psi_q_b2 = (const float*)d_in[9];
  const float* q_w      = (const float*)d_in[10];
  const float* q_b      = (const float*)d_in[11];
  const float* k_w      = (const float*)d_in[12];
  // k_b (d_in[13]) unused: constant score shift cancels in softmax
  const float* v_w      = (const float*)d_in[14];
  const float* v_b      = (const float*)d_in[15];
  const float* phi_w1   = (const float*)d_in[16];
  const float* phi_b1   = (const float*)d_in[17];
  const float* phi_w2   = (const float*)d_in[18];
  const float* phi_b2   = (const float*)d_in[19];
  float* out = (float*)d_out;

  char* ws = (char*)d_ws;
  unsigned short* w1p = (unsigned short*)(ws);                 // 131072
  unsigned short* w2p = (unsigned short*)(ws + 131072);        // 524288
  float* qk   = (float*)(ws + 655360);                         // 65536
  float* part = (float*)(ws + 720896);                         // 4194304
  float* esum = (float*)(ws + 4915200);                        // 8192
  float* h2g  = (float*)(ws + 4923392);                        // 65536
  float* qvg  = (float*)(ws + 4988928);                        // 65536
  float* ub   = (float*)(ws + 5054464);                        // 65536
  float* zb   = (float*)(ws + 5120000);                        // 65536
  float* hb   = (float*)(ws + 5185536);                        // 65536

  hipLaunchKernelGGL(k_prep, dim3(1024), dim3(256), 0, stream,
                     psi_x_w1, psi_x_w2, w1p, w2p);
  hipLaunchKernelGGL(k_q2, dim3(32, 8), dim3(64), 0, stream,
                     x_query, psi_q_w1, psi_q_b1, psi_q_w2, psi_q_b2, h2g);
  hipLaunchKernelGGL(k_q3, dim3(32, 8), dim3(64), 0, stream,
                     h2g, q_w, q_b, qvg);
  hipLaunchKernelGGL(k_q4, dim3(32, 8), dim3(64), 0, stream,
                     qvg, k_w, qk);
  hipLaunchKernelGGL(k_main, dim3(NT_, B_), dim3(512), 0, stream,
                     x_items, w1p, psi_x_b1, w2p, psi_x_b2, qk, part, esum);
  hipLaunchKernelGGL(k_fu, dim3(32, 4), dim3(128), 0, stream,
                     part, esum, ub);
  hipLaunchKernelGGL(k_fz, dim3(32, 8), dim3(64), 0, stream,
                     ub, v_w, v_b, zb);
  hipLaunchKernelGGL(k_fh, dim3(32, 8), dim3(64), 0, stream,
                     zb, phi_w1, phi_b1, hb);
  hipLaunchKernelGGL(k_fo, dim3(32, 16), dim3(64), 0, stream,
                     hb, phi_w2, phi_b2, out);
}

// Round 2
// 568.031 us; speedup vs baseline: 1.1592x; 1.1592x over previous
//
#include <hip/hip_runtime.h>
#include <hip/hip_bf16.h>

#define B_ 32
#define N_ 8192
#define DI_ 128
#define D_ 512
#define NC_ 1000
#define TN_ 128          // items per output tile (per block)
#define SN_ 32           // items per sub-tile (acc[8] = 32 VGPR -> no spill at 4 waves/SIMD)
#define NSUB_ 4          // sub-tiles per block
#define NT_ 64           // tiles = N_/TN_
#define XROW_ 136        // x_lds row stride in shorts (pad +8)

typedef short s8v __attribute__((ext_vector_type(8)));
typedef float f4v __attribute__((ext_vector_type(4)));

__device__ __forceinline__ unsigned short f2bf(float f){
  union { float f; unsigned u; } c; c.f = f;
  unsigned r = c.u + 0x7fffu + ((c.u >> 16) & 1u);
  return (unsigned short)(r >> 16);
}

// hardware v_cvt_pk_bf16_f32: 2 floats -> packed bf16 (RNE), a in low 16
__device__ __forceinline__ unsigned pk2bf(float a, float b){
  float2 f; f.x = a; f.y = b;
  __hip_bfloat162 h = __float22bfloat162_rn(f);
  union { __hip_bfloat162 h; unsigned u; } c; c.h = h;
  return c.u;
}

// exact GELU: 0.5x(1+erf(x/sqrt2)); Abramowitz-Stegun 7.1.26, |err| <= 1.5e-7
__device__ __forceinline__ float gelu_f(float x){
  float ax = fabsf(x) * 0.70710678118654752f;
  float t = __builtin_amdgcn_rcpf(1.0f + 0.3275911f * ax);
  float poly = ((((1.061405429f*t - 1.453152027f)*t + 1.421413741f)*t
                 - 0.284496736f)*t + 0.254829592f)*t;
  float e = __expf(-ax*ax);
  float erf_ax = 1.0f - poly*e;
  erf_ax = (x >= 0.0f) ? erf_ax : -erf_ax;
  return 0.5f * x * (1.0f + erf_ax);
}

__device__ __forceinline__ float wsum64(float v){
  #pragma unroll
  for (int off = 32; off; off >>= 1) v += __shfl_xor(v, off, 64);
  return v;
}

// ---------------- prep: convert psi_x w1 to bf16 in MFMA fragment order ----------------
__global__ void k_prep(const float* __restrict__ w1, unsigned short* __restrict__ w1p){
  int i = blockIdx.x * 256 + threadIdx.x;
  if (i < D_*DI_){
    int j = i / DI_, kc = i % DI_;
    int kk = kc >> 5, q = (kc >> 3) & 3, s = kc & 7;
    w1p[((kk*D_ + j)*4 + q)*8 + s] = f2bf(w1[i]);
  }
}

// ---------------- fused query chain: one block per batch, 512 threads ----------------
// h1q = gelu(xq*w1q + b1q); h2 = W2q h1q + b2q; qv = Qw h2 + qb;
// qk[i] = scale * sum_d qv[d] Kw[d,i]; qkw2[k] = sum_i qk[i] W2[i,k]
__global__ __launch_bounds__(512)
void k_qa(const float* __restrict__ xq,
          const float* __restrict__ w1q, const float* __restrict__ b1q,
          const float* __restrict__ w2q, const float* __restrict__ b2q,
          const float* __restrict__ qw,  const float* __restrict__ qb,
          const float* __restrict__ kw,  const float* __restrict__ w2,
          float* __restrict__ qkw2g){
  const int b = blockIdx.x, t = threadIdx.x;
  __shared__ float va[D_], vb_[D_];
  // A: h1q
  va[t] = gelu_f(xq[b] * w1q[t] + b1q[t]);
  __syncthreads();
  // B: h2 (row per thread)
  {
    const float4* rw = (const float4*)(w2q + (size_t)t*D_);
    float a0 = 0.f, a1 = 0.f;
    #pragma unroll 4
    for (int kk = 0; kk < 128; kk += 2){
      float4 h0 = *(const float4*)&va[kk*4];     float4 w0 = rw[kk];
      float4 h1 = *(const float4*)&va[kk*4+4];   float4 w1 = rw[kk+1];
      a0 += w0.x*h0.x + w0.y*h0.y + w0.z*h0.z + w0.w*h0.w;
      a1 += w1.x*h1.x + w1.y*h1.y + w1.z*h1.z + w1.w*h1.w;
    }
    vb_[t] = a0 + a1 + b2q[t];
  }
  __syncthreads();
  // C: qv (row per thread)
  float qv;
  {
    const float4* rw = (const float4*)(qw + (size_t)t*D_);
    float a0 = 0.f, a1 = 0.f;
    #pragma unroll 4
    for (int kk = 0; kk < 128; kk += 2){
      float4 h0 = *(const float4*)&vb_[kk*4];    float4 w0 = rw[kk];
      float4 h1 = *(const float4*)&vb_[kk*4+4];  float4 w1 = rw[kk+1];
      a0 += w0.x*h0.x + w0.y*h0.y + w0.z*h0.z + w0.w*h0.w;
      a1 += w1.x*h1.x + w1.y*h1.y + w1.z*h1.z + w1.w*h1.w;
    }
    qv = a0 + a1 + qb[t];
  }
  __syncthreads();           // vb_ consumed by all before overwrite? (vb_ read in C, rewritten below via va path)
  va[t] = qv;
  __syncthreads();
  // D: qk (coalesced over t)
  {
    float a0=0.f, a1=0.f, a2=0.f, a3=0.f;
    for (int d = 0; d < D_; d += 4){
      a0 += va[d]   * kw[(size_t)(d)  *D_ + t];
      a1 += va[d+1] * kw[(size_t)(d+1)*D_ + t];
      a2 += va[d+2] * kw[(size_t)(d+2)*D_ + t];
      a3 += va[d+3] * kw[(size_t)(d+3)*D_ + t];
    }
    vb_[t] = 0.04419417382415922f * ((a0+a1)+(a2+a3));   // 512^-0.5 folded in
  }
  __syncthreads();
  // E: qkw2 (coalesced over t)
  {
    float a0=0.f, a1=0.f, a2=0.f, a3=0.f;
    for (int i = 0; i < D_; i += 4){
      a0 += vb_[i]   * w2[(size_t)(i)  *D_ + t];
      a1 += vb_[i+1] * w2[(size_t)(i+1)*D_ + t];
      a2 += vb_[i+2] * w2[(size_t)(i+2)*D_ + t];
      a3 += vb_[i+3] * w2[(size_t)(i+3)*D_ + t];
    }
    qkw2g[b*D_ + t] = (a0+a1)+(a2+a3);
  }
}

// ---------------- main: GEMM1 + gelu + score(qkw2.h1) + weighted hbar accumulate ----------------
// GEMM2 eliminated algebraically: u = W2 @ (sum e*h1)/sum(e) + b2, applied once per batch in k_fw.
// LDS ~23 KB, acc[8]+zacc[4] => ~100 VGPR peak -> 2 blocks/CU at launch_bounds(512,4), no spill.
__global__ __launch_bounds__(512, 4)
void k_main(const float* __restrict__ x,                 // [B,N,DI]
            const unsigned short* __restrict__ w1p,      // packed bf16
            const float* __restrict__ b1,
            const float* __restrict__ qkw2,              // [B,D]
            float* __restrict__ part,                    // [B,NT,D] : sum e*h1 partials
            float* __restrict__ esum){                   // [B,NT]
  const int tile = blockIdx.x;       // 0..63
  const int b = blockIdx.y;          // 0..31
  const int t = threadIdx.x;         // 0..511
  const int lane = t & 63;
  const int wid = t >> 6;            // 0..7
  const int ln = lane & 15;
  const int q  = lane >> 4;          // 0..3

  __shared__ unsigned short x_lds[2][SN_ * XROW_];  // 2 x 8704 B
  __shared__ float s_ws[8][SN_];                    // 1024 B
  __shared__ float e_lds[SN_];                      // 128 B
  __shared__ float sb1[D_];                         // 2048 B
  __shared__ float sq2[D_];                         // 2048 B

  const int jb = wid * 64;              // this wave's 64-col j block
  const unsigned short* w1base = w1p + (jb + ln)*32 + q*8;
  const float* xbase = x + ((size_t)b * N_ + tile * TN_) * DI_;

  // invariants to LDS + stage sub 0
  sb1[t] = b1[t];
  sq2[t] = qkw2[b*D_ + t];
  {
    const float4* x4 = (const float4*)xbase;
    #pragma unroll
    for (int i = 0; i < 2; ++i){
      const int f = i*512 + t;            // 1024 float4 per sub-tile
      float4 v = x4[f];
      const int m = f >> 5;
      const int k = (f & 31) << 2;
      uint2 pk;
      pk.x = pk2bf(v.x, v.y);
      pk.y = pk2bf(v.z, v.w);
      *(uint2*)&x_lds[0][m*XROW_ + k] = pk;
    }
  }
  __syncthreads();

  f4v zacc[4];
  #pragma unroll
  for (int i = 0; i < 4; ++i) zacc[i] = (f4v){0.f,0.f,0.f,0.f};
  float etot = 0.f;

  for (int s = 0; s < NSUB_; ++s){
    const unsigned short* xb = x_lds[s & 1];

    f4v acc[8];
    #pragma unroll
    for (int i = 0; i < 8; ++i) acc[i] = (f4v){0.f,0.f,0.f,0.f};

    // ---- GEMM1: h1^T[j,m] = sum_k w1[j,k] * x[m,k] ----
    #pragma unroll
    for (int kk = 0; kk < 4; ++kk){
      const int k = kk*32 + q*8;
      s8v aw[4];
      #pragma unroll
      for (int jt = 0; jt < 4; ++jt)
        aw[jt] = *(const s8v*)(w1base + kk*(D_*32) + jt*(16*32));
      s8v bx[2];
      #pragma unroll
      for (int mi = 0; mi < 2; ++mi)
        bx[mi] = *(const s8v*)&xb[(mi*16 + ln)*XROW_ + k];
      #pragma unroll
      for (int jt = 0; jt < 4; ++jt)
        #pragma unroll
        for (int mi = 0; mi < 2; ++mi)
          acc[jt*2+mi] = __builtin_amdgcn_mfma_f32_16x16x32_bf16(aw[jt], bx[mi], acc[jt*2+mi], 0,0,0);
    }

    // ---- prefetch next sub-tile into regs (HBM latency hides under gelu/score) ----
    float4 pv0, pv1;
    if (s + 1 < NSUB_){
      const float4* x4 = (const float4*)(xbase + (size_t)(s+1)*SN_*DI_);
      pv0 = x4[t];
      pv1 = x4[512 + t];
    }

    // ---- bias + exact GELU (in place) + score partial over this wave's 64 j ----
    float sp0 = 0.f, sp1 = 0.f;
    #pragma unroll
    for (int jt = 0; jt < 4; ++jt){
      const f4v bv = *(const f4v*)&sb1[jb + jt*16 + q*4];
      const f4v qv = *(const f4v*)&sq2[jb + jt*16 + q*4];
      #pragma unroll
      for (int mi = 0; mi < 2; ++mi){
        f4v a = acc[jt*2+mi];
        a[0] = gelu_f(a[0] + bv[0]);
        a[1] = gelu_f(a[1] + bv[1]);
        a[2] = gelu_f(a[2] + bv[2]);
        a[3] = gelu_f(a[3] + bv[3]);
        acc[jt*2+mi] = a;
        const float d = qv[0]*a[0] + qv[1]*a[1] + qv[2]*a[2] + qv[3]*a[3];
        if (mi == 0) sp0 += d; else sp1 += d;
      }
    }
    // reduce over q lanes (xor 16,32): full-j partial per m = mi*16+ln
    sp0 += __shfl_xor(sp0, 16, 64); sp0 += __shfl_xor(sp0, 32, 64);
    sp1 += __shfl_xor(sp1, 16, 64); sp1 += __shfl_xor(sp1, 32, 64);
    if (q == 0) s_ws[wid][lane] = sp0;        // lane = ln      -> m = ln
    if (q == 1) s_ws[wid][lane] = sp1;        // lane = 16+ln   -> m = 16+ln

    // ---- write prefetched x to the other LDS buffer ----
    if (s + 1 < NSUB_){
      unsigned short* xn = &x_lds[(s+1) & 1][0];
      int f = t, m = f >> 5, k = (f & 31) << 2;
      uint2 pk;
      pk.x = pk2bf(pv0.x, pv0.y);
      pk.y = pk2bf(pv0.z, pv0.w);
      *(uint2*)&xn[m*XROW_ + k] = pk;
      f = 512 + t; m = f >> 5; k = (f & 31) << 2;
      pk.x = pk2bf(pv1.x, pv1.y);
      pk.y = pk2bf(pv1.z, pv1.w);
      *(uint2*)&xn[m*XROW_ + k] = pk;
    }
    __syncthreads();     // (A) scores complete, staging complete

    if (t < SN_){
      float sc = 0.f;
      #pragma unroll
      for (int w = 0; w < 8; ++w) sc += s_ws[w][t];
      e_lds[t] = __expf(sc);     // constant shift (qk.b2, k_b) cancels in softmax
    }
    __syncthreads();     // (B) e ready

    if (wid == 0){
      float v = (lane < SN_) ? e_lds[lane] : 0.f;
      etot += wsum64(v);
    }

    // ---- weighted hbar accumulate: zacc[j] += sum_m e[m]*h1[m,j] (per-lane mi part) ----
    {
      const float em0 = e_lds[ln];
      const float em1 = e_lds[16 + ln];
      #pragma unroll
      for (int jt = 0; jt < 4; ++jt){
        const f4v a0 = acc[jt*2+0];
        const f4v a1 = acc[jt*2+1];
        #pragma unroll
        for (int r = 0; r < 4; ++r)
          zacc[jt][r] += em0*a0[r] + em1*a1[r];
      }
    }
    // no barrier needed: next iter's e_lds write is after its own barrier (A)
  }

  if (t == 0) esum[b*NT_ + tile] = etot;

  // reduce zacc over ln lanes (same q => same j set), write 4x float4 per q-lane
  #pragma unroll
  for (int jt = 0; jt < 4; ++jt){
    #pragma unroll
    for (int r = 0; r < 4; ++r){
      float v = zacc[jt][r];
      v += __shfl_xor(v, 1, 64);
      v += __shfl_xor(v, 2, 64);
      v += __shfl_xor(v, 4, 64);
      v += __shfl_xor(v, 8, 64);
      zacc[jt][r] = v;
    }
    if (ln == 0){
      float4 o; o.x = zacc[jt][0]; o.y = zacc[jt][1]; o.z = zacc[jt][2]; o.w = zacc[jt][3];
      *(float4*)&part[((size_t)(b*NT_ + tile))*D_ + jb + jt*16 + q*4] = o;
    }
  }
}

// ---------------- final path ----------------
// u[b][k] = (1/sum e) * sum_tl part[b][tl][k];  grid (32,4) x 128
__global__ __launch_bounds__(128)
void k_fu(const float* __restrict__ part, const float* __restrict__ esum,
          float* __restrict__ u){
  const int b = blockIdx.x, sl = blockIdx.y, t = threadIdx.x;
  float p = esum[b*NT_ + (t & 63)];
  p = wsum64(p);
  const float linv = 1.0f / p;
  const int col = sl*128 + t;
  const float* pb = part + (size_t)b*NT_*D_ + col;
  float s = 0.f;
  for (int tl = 0; tl < NT_; ++tl) s += pb[tl*D_];
  u[b*D_ + col] = s * linv;
}

// u2 = W2 @ u + b2  (the deferred psi_x second linear);  grid (32,8) x 64
__global__ __launch_bounds__(64)
void k_fw(const float* __restrict__ u, const float* __restrict__ w2,
          const float* __restrict__ b2x, float* __restrict__ u2){
  const int b = blockIdx.x, sl = blockIdx.y, t = threadIdx.x;
  __shared__ float su[D_];
  #pragma unroll
  for (int i = 0; i < 8; ++i) su[i*64 + t] = u[b*D_ + i*64 + t];
  __syncthreads();
  const int d = sl*64 + t;
  const float4* rw = (const float4*)(w2 + (size_t)d*D_);
  float a = 0.f;
  for (int kk = 0; kk < 128; ++kk){
    float4 uv = *(const float4*)&su[kk*4];
    float4 wv = rw[kk];
    a += wv.x*uv.x + wv.y*uv.y + wv.z*uv.z + wv.w*uv.w;
  }
  u2[b*D_ + d] = a + b2x[d];
}

// z = vw @ u2 + vb;  grid (32,8) x 64
__global__ __launch_bounds__(64)
void k_fz(const float* __restrict__ u, const float* __restrict__ vw,
          const float* __restrict__ vb, float* __restrict__ z){
  const int b = blockIdx.x, sl = blockIdx.y, t = threadIdx.x;
  __shared__ float su[D_];
  #pragma unroll
  for (int i = 0; i < 8; ++i) su[i*64 + t] = u[b*D_ + i*64 + t];
  __syncthreads();
  const int d = sl*64 + t;
  const float4* rw = (const float4*)(vw + (size_t)d*D_);
  float a = 0.f;
  for (int kk = 0; kk < 128; ++kk){
    float4 uv = *(const float4*)&su[kk*4];
    float4 wv = rw[kk];
    a += wv.x*uv.x + wv.y*uv.y + wv.z*uv.z + wv.w*uv.w;
  }
  z[b*D_ + d] = a + vb[d];
}

// h = gelu(pw1 @ z + pb1);  grid (32,8) x 64
__global__ __launch_bounds__(64)
void k_fh(const float* __restrict__ z, const float* __restrict__ pw1,
          const float* __restrict__ pb1, float* __restrict__ h){
  const int b = blockIdx.x, sl = blockIdx.y, t = threadIdx.x;
  __shared__ float sz[D_];
  #pragma unroll
  for (int i = 0; i < 8; ++i) sz[i*64 + t] = z[b*D_ + i*64 + t];
  __syncthreads();
  const int d = sl*64 + t;
  const float4* rw = (const float4*)(pw1 + (size_t)d*D_);
  float a = 0.f;
  for (int kk = 0; kk < 128; ++kk){
    float4 zv = *(const float4*)&sz[kk*4];
    float4 wv = rw[kk];
    a += wv.x*zv.x + wv.y*zv.y + wv.z*zv.z + wv.w*zv.w;
  }
  h[b*D_ + d] = gelu_f(a + pb1[d]);
}

// out = pw2 @ h + pb2;  grid (32,16) x 64
__global__ __launch_bounds__(64)
void k_fo(const float* __restrict__ h, const float* __restrict__ pw2,
          const float* __restrict__ pb2, float* __restrict__ out){
  const int b = blockIdx.x, sl = blockIdx.y, t = threadIdx.x;
  __shared__ float sh[D_];
  #pragma unroll
  for (int i = 0; i < 8; ++i) sh[i*64 + t] = h[b*D_ + i*64 + t];
  __syncthreads();
  const int c = sl*64 + t;
  if (c < NC_){
    const float4* rw = (const float4*)(pw2 + (size_t)c*D_);
    float a = 0.f;
    for (int kk = 0; kk < 128; ++kk){
      float4 hv = *(const float4*)&sh[kk*4];
      float4 wv = rw[kk];
      a += wv.x*hv.x + wv.y*hv.y + wv.z*hv.z + wv.w*hv.w;
    }
    out[(size_t)b*NC_ + c] = a + pb2[c];
  }
}

extern "C" void kernel_launch(void* const* d_in, const int* in_sizes, int n_in,
                              void* d_out, int out_size, void* d_ws, size_t ws_size,
                              hipStream_t stream) {
  (void)in_sizes; (void)n_in; (void)out_size; (void)ws_size;
  const float* x_items  = (const float*)d_in[0];
  const float* x_query  = (const float*)d_in[1];
  const float* psi_x_w1 = (const float*)d_in[2];
  const float* psi_x_b1 = (const float*)d_in[3];
  const float* psi_x_w2 = (const float*)d_in[4];
  const float* psi_x_b2 = (const float*)d_in[5];
  const float* psi_q_w1 = (const float*)d_in[6];
  const float* psi_q_b1 = (const float*)d_in[7];
  const float* psi_q_w2 = (const float*)d_in[8];
  const float* psi_q_b2 = (const float*)d_in[9];
  const float* q_w      = (const float*)d_in[10];
  const float* q_b      = (const float*)d_in[11];
  const float* k_w      = (const float*)d_in[12];
  // k_b (d_in[13]) unused: constant score shift cancels in softmax
  const float* v_w      = (const float*)d_in[14];
  const float* v_b      = (const float*)d_in[15];
  const float* phi_w1   = (const float*)d_in[16];
  const float* phi_b1   = (const float*)d_in[17];
  const float* phi_w2   = (const float*)d_in[18];
  const float* phi_b2   = (const float*)d_in[19];
  float* out = (float*)d_out;

  char* ws = (char*)d_ws;
  unsigned short* w1p = (unsigned short*)(ws);                 // 131072
  float* qkw2 = (float*)(ws + 131072);                         // 65536
  float* part = (float*)(ws + 196608);                         // 4194304
  float* esum = (float*)(ws + 4390912);                        // 8192
  float* ub   = (float*)(ws + 4399104);                        // 65536
  float* u2b  = (float*)(ws + 4464640);                        // 65536
  float* zb   = (float*)(ws + 4530176);                        // 65536
  float* hb   = (float*)(ws + 4595712);                        // 65536

  hipLaunchKernelGGL(k_prep, dim3(256), dim3(256), 0, stream,
                     psi_x_w1, w1p);
  hipLaunchKernelGGL(k_qa, dim3(32), dim3(512), 0, stream,
                     x_query, psi_q_w1, psi_q_b1, psi_q_w2, psi_q_b2,
                     q_w, q_b, k_w, psi_x_w2, qkw2);
  hipLaunchKernelGGL(k_main, dim3(NT_, B_), dim3(512), 0, stream,
                     x_items, w1p, psi_x_b1, qkw2, part, esum);
  hipLaunchKernelGGL(k_fu, dim3(32, 4), dim3(128), 0, stream,
                     part, esum, ub);
  hipLaunchKernelGGL(k_fw, dim3(32, 8), dim3(64), 0, stream,
                     ub, psi_x_w2, psi_x_b2, u2b);
  hipLaunchKernelGGL(k_fz, dim3(32, 8), dim3(64), 0, stream,
                     u2b, v_w, v_b, zb);
  hipLaunchKernelGGL(k_fh, dim3(32, 8), dim3(64), 0, stream,
                     zb, phi_w1, phi_b1, hb);
  hipLaunchKernelGGL(k_fo, dim3(32, 16), dim3(64), 0, stream,
                     hb, phi_w2, phi_b2, out);
}

// Round 3
// 564.018 us; speedup vs baseline: 1.1674x; 1.0071x over previous
//
#include <hip/hip_runtime.h>
#include <hip/hip_bf16.h>

#define B_ 32
#define N_ 8192
#define DI_ 128
#define D_ 512
#define NC_ 1000
#define TN_ 128          // items per output tile (per block)
#define SN_ 32           // items per sub-tile
#define NSUB_ 4          // sub-tiles per block
#define NT_ 64           // tiles = N_/TN_
#define XROW_ 136        // x_lds row stride in shorts (pad +8)

typedef short s8v __attribute__((ext_vector_type(8)));
typedef float f4v __attribute__((ext_vector_type(4)));

__device__ __forceinline__ unsigned short f2bf(float f){
  union { float f; unsigned u; } c; c.f = f;
  unsigned r = c.u + 0x7fffu + ((c.u >> 16) & 1u);
  return (unsigned short)(r >> 16);
}

// hardware v_cvt_pk_bf16_f32: 2 floats -> packed bf16 (RNE), a in low 16
__device__ __forceinline__ unsigned pk2bf(float a, float b){
  float2 f; f.x = a; f.y = b;
  __hip_bfloat162 h = __float22bfloat162_rn(f);
  union { __hip_bfloat162 h; unsigned u; } c; c.h = h;
  return c.u;
}

// exact GELU: 0.5x(1+erf(x/sqrt2)); Abramowitz-Stegun 7.1.26, |err| <= 1.5e-7
__device__ __forceinline__ float gelu_f(float x){
  float ax = fabsf(x) * 0.70710678118654752f;
  float t = __builtin_amdgcn_rcpf(1.0f + 0.3275911f * ax);
  float poly = ((((1.061405429f*t - 1.453152027f)*t + 1.421413741f)*t
                 - 0.284496736f)*t + 0.254829592f)*t;
  float e = __expf(-ax*ax);
  float erf_ax = 1.0f - poly*e;
  erf_ax = (x >= 0.0f) ? erf_ax : -erf_ax;
  return 0.5f * x * (1.0f + erf_ax);
}

__device__ __forceinline__ float wsum64(float v){
  #pragma unroll
  for (int off = 32; off; off >>= 1) v += __shfl_xor(v, off, 64);
  return v;
}

// ---------------- prep: convert psi_x w1 to bf16 in MFMA fragment order ----------------
__global__ void k_prep(const float* __restrict__ w1, unsigned short* __restrict__ w1p){
  int i = blockIdx.x * 256 + threadIdx.x;
  if (i < D_*DI_){
    int j = i / DI_, kc = i % DI_;
    int kk = kc >> 5, q = (kc >> 3) & 3, s = kc & 7;
    w1p[((kk*D_ + j)*4 + q)*8 + s] = f2bf(w1[i]);
  }
}

// ---------------- fused query chain: one block per batch, 512 threads ----------------
// h1q = gelu(xq*w1q + b1q); h2 = W2q h1q + b2q; qv = Qw h2 + qb;
// qk[i] = scale * sum_d qv[d] Kw[d,i]; qkw2[k] = sum_i qk[i] W2[i,k]
__global__ __launch_bounds__(512)
void k_qa(const float* __restrict__ xq,
          const float* __restrict__ w1q, const float* __restrict__ b1q,
          const float* __restrict__ w2q, const float* __restrict__ b2q,
          const float* __restrict__ qw,  const float* __restrict__ qb,
          const float* __restrict__ kw,  const float* __restrict__ w2,
          float* __restrict__ qkw2g){
  const int b = blockIdx.x, t = threadIdx.x;
  __shared__ float va[D_], vb_[D_];
  // A: h1q
  va[t] = gelu_f(xq[b] * w1q[t] + b1q[t]);
  __syncthreads();
  // B: h2 (row per thread)
  {
    const float4* rw = (const float4*)(w2q + (size_t)t*D_);
    float a0 = 0.f, a1 = 0.f;
    #pragma unroll 4
    for (int kk = 0; kk < 128; kk += 2){
      float4 h0 = *(const float4*)&va[kk*4];     float4 w0 = rw[kk];
      float4 h1 = *(const float4*)&va[kk*4+4];   float4 w1 = rw[kk+1];
      a0 += w0.x*h0.x + w0.y*h0.y + w0.z*h0.z + w0.w*h0.w;
      a1 += w1.x*h1.x + w1.y*h1.y + w1.z*h1.z + w1.w*h1.w;
    }
    vb_[t] = a0 + a1 + b2q[t];
  }
  __syncthreads();
  // C: qv (row per thread)
  float qv;
  {
    const float4* rw = (const float4*)(qw + (size_t)t*D_);
    float a0 = 0.f, a1 = 0.f;
    #pragma unroll 4
    for (int kk = 0; kk < 128; kk += 2){
      float4 h0 = *(const float4*)&vb_[kk*4];    float4 w0 = rw[kk];
      float4 h1 = *(const float4*)&vb_[kk*4+4];  float4 w1 = rw[kk+1];
      a0 += w0.x*h0.x + w0.y*h0.y + w0.z*h0.z + w0.w*h0.w;
      a1 += w1.x*h1.x + w1.y*h1.y + w1.z*h1.z + w1.w*h1.w;
    }
    qv = a0 + a1 + qb[t];
  }
  __syncthreads();
  va[t] = qv;
  __syncthreads();
  // D: qk (coalesced over t)
  {
    float a0=0.f, a1=0.f, a2=0.f, a3=0.f;
    for (int d = 0; d < D_; d += 4){
      a0 += va[d]   * kw[(size_t)(d)  *D_ + t];
      a1 += va[d+1] * kw[(size_t)(d+1)*D_ + t];
      a2 += va[d+2] * kw[(size_t)(d+2)*D_ + t];
      a3 += va[d+3] * kw[(size_t)(d+3)*D_ + t];
    }
    vb_[t] = 0.04419417382415922f * ((a0+a1)+(a2+a3));   // 512^-0.5 folded in
  }
  __syncthreads();
  // E: qkw2 (coalesced over t)
  {
    float a0=0.f, a1=0.f, a2=0.f, a3=0.f;
    for (int i = 0; i < D_; i += 4){
      a0 += vb_[i]   * w2[(size_t)(i)  *D_ + t];
      a1 += vb_[i+1] * w2[(size_t)(i+1)*D_ + t];
      a2 += vb_[i+2] * w2[(size_t)(i+2)*D_ + t];
      a3 += vb_[i+3] * w2[(size_t)(i+3)*D_ + t];
    }
    qkw2g[b*D_ + t] = (a0+a1)+(a2+a3);
  }
}

// ---------------- main: GEMM1 + gelu + score(qkw2.h1) + weighted hbar accumulate ----------------
// GEMM2 eliminated algebraically: u = W2 @ (sum e*h1)/sum(e) + b2, applied once per batch in k_tail.
// launch_bounds(512,2): 256-reg cap; natural allocation ~110-130 regs -> no spill.
// ((512,4) capped arch VGPRs at 64 and spilled ~270 MB/dispatch in rounds 1-2.)
__global__ __launch_bounds__(512, 2)
void k_main(const float* __restrict__ x,                 // [B,N,DI]
            const unsigned short* __restrict__ w1p,      // packed bf16
            const float* __restrict__ b1,
            const float* __restrict__ qkw2,              // [B,D]
            float* __restrict__ part,                    // [B,NT,D] : sum e*h1 partials
            float* __restrict__ esum){                   // [B,NT]
  const int tile = blockIdx.x;       // 0..63
  const int b = blockIdx.y;          // 0..31
  const int t = threadIdx.x;         // 0..511
  const int lane = t & 63;
  const int wid = t >> 6;            // 0..7
  const int ln = lane & 15;
  const int q  = lane >> 4;          // 0..3

  __shared__ unsigned short x_lds[2][SN_ * XROW_];  // 2 x 8704 B
  __shared__ float s_ws[8][SN_];                    // 1024 B
  __shared__ float e_lds[SN_];                      // 128 B
  __shared__ float sb1[D_];                         // 2048 B
  __shared__ float sq2[D_];                         // 2048 B

  const int jb = wid * 64;              // this wave's 64-col j block
  const unsigned short* w1base = w1p + (jb + ln)*32 + q*8;
  const float* xbase = x + ((size_t)b * N_ + tile * TN_) * DI_;

  // invariants to LDS + stage sub 0
  sb1[t] = b1[t];
  sq2[t] = qkw2[b*D_ + t];
  {
    const float4* x4 = (const float4*)xbase;
    #pragma unroll
    for (int i = 0; i < 2; ++i){
      const int f = i*512 + t;            // 1024 float4 per sub-tile
      float4 v = x4[f];
      const int m = f >> 5;
      const int k = (f & 31) << 2;
      uint2 pk;
      pk.x = pk2bf(v.x, v.y);
      pk.y = pk2bf(v.z, v.w);
      *(uint2*)&x_lds[0][m*XROW_ + k] = pk;
    }
  }
  __syncthreads();

  f4v zacc[4];
  #pragma unroll
  for (int i = 0; i < 4; ++i) zacc[i] = (f4v){0.f,0.f,0.f,0.f};
  float etot = 0.f;

  for (int s = 0; s < NSUB_; ++s){
    const unsigned short* xb = x_lds[s & 1];

    f4v acc[8];
    #pragma unroll
    for (int i = 0; i < 8; ++i) acc[i] = (f4v){0.f,0.f,0.f,0.f};

    // ---- GEMM1: h1^T[j,m] = sum_k w1[j,k] * x[m,k] ----
    #pragma unroll
    for (int kk = 0; kk < 4; ++kk){
      const int k = kk*32 + q*8;
      s8v aw[4];
      #pragma unroll
      for (int jt = 0; jt < 4; ++jt)
        aw[jt] = *(const s8v*)(w1base + kk*(D_*32) + jt*(16*32));
      s8v bx[2];
      #pragma unroll
      for (int mi = 0; mi < 2; ++mi)
        bx[mi] = *(const s8v*)&xb[(mi*16 + ln)*XROW_ + k];
      #pragma unroll
      for (int jt = 0; jt < 4; ++jt)
        #pragma unroll
        for (int mi = 0; mi < 2; ++mi)
          acc[jt*2+mi] = __builtin_amdgcn_mfma_f32_16x16x32_bf16(aw[jt], bx[mi], acc[jt*2+mi], 0,0,0);
    }

    // ---- prefetch next sub-tile into regs (HBM latency hides under gelu/score) ----
    float4 pv0, pv1;
    if (s + 1 < NSUB_){
      const float4* x4 = (const float4*)(xbase + (size_t)(s+1)*SN_*DI_);
      pv0 = x4[t];
      pv1 = x4[512 + t];
    }

    // ---- bias + exact GELU (in place) + score partial over this wave's 64 j ----
    float sp0 = 0.f, sp1 = 0.f;
    #pragma unroll
    for (int jt = 0; jt < 4; ++jt){
      const f4v bv = *(const f4v*)&sb1[jb + jt*16 + q*4];
      const f4v qv = *(const f4v*)&sq2[jb + jt*16 + q*4];
      #pragma unroll
      for (int mi = 0; mi < 2; ++mi){
        f4v a = acc[jt*2+mi];
        a[0] = gelu_f(a[0] + bv[0]);
        a[1] = gelu_f(a[1] + bv[1]);
        a[2] = gelu_f(a[2] + bv[2]);
        a[3] = gelu_f(a[3] + bv[3]);
        acc[jt*2+mi] = a;
        const float d = qv[0]*a[0] + qv[1]*a[1] + qv[2]*a[2] + qv[3]*a[3];
        if (mi == 0) sp0 += d; else sp1 += d;
      }
    }
    // reduce over q lanes (xor 16,32): full-j partial per m = mi*16+ln
    sp0 += __shfl_xor(sp0, 16, 64); sp0 += __shfl_xor(sp0, 32, 64);
    sp1 += __shfl_xor(sp1, 16, 64); sp1 += __shfl_xor(sp1, 32, 64);
    if (q == 0) s_ws[wid][lane] = sp0;        // lane = ln      -> m = ln
    if (q == 1) s_ws[wid][lane] = sp1;        // lane = 16+ln   -> m = 16+ln

    // ---- write prefetched x to the other LDS buffer ----
    if (s + 1 < NSUB_){
      unsigned short* xn = &x_lds[(s+1) & 1][0];
      int f = t, m = f >> 5, k = (f & 31) << 2;
      uint2 pk;
      pk.x = pk2bf(pv0.x, pv0.y);
      pk.y = pk2bf(pv0.z, pv0.w);
      *(uint2*)&xn[m*XROW_ + k] = pk;
      f = 512 + t; m = f >> 5; k = (f & 31) << 2;
      pk.x = pk2bf(pv1.x, pv1.y);
      pk.y = pk2bf(pv1.z, pv1.w);
      *(uint2*)&xn[m*XROW_ + k] = pk;
    }
    __syncthreads();     // (A) scores complete, staging complete

    if (t < SN_){
      float sc = 0.f;
      #pragma unroll
      for (int w = 0; w < 8; ++w) sc += s_ws[w][t];
      e_lds[t] = __expf(sc);     // constant shift (qk.b2, k_b) cancels in softmax
    }
    __syncthreads();     // (B) e ready

    if (wid == 0){
      float v = (lane < SN_) ? e_lds[lane] : 0.f;
      etot += wsum64(v);
    }

    // ---- weighted hbar accumulate: zacc[j] += sum_m e[m]*h1[m,j] (per-lane mi part) ----
    {
      const float em0 = e_lds[ln];
      const float em1 = e_lds[16 + ln];
      #pragma unroll
      for (int jt = 0; jt < 4; ++jt){
        const f4v a0 = acc[jt*2+0];
        const f4v a1 = acc[jt*2+1];
        #pragma unroll
        for (int r = 0; r < 4; ++r)
          zacc[jt][r] += em0*a0[r] + em1*a1[r];
      }
    }
    // no barrier needed: next iter's e_lds write is after its own barrier (A)
  }

  if (t == 0) esum[b*NT_ + tile] = etot;

  // reduce zacc over ln lanes (same q => same j set), write 4x float4 per q-lane
  #pragma unroll
  for (int jt = 0; jt < 4; ++jt){
    #pragma unroll
    for (int r = 0; r < 4; ++r){
      float v = zacc[jt][r];
      v += __shfl_xor(v, 1, 64);
      v += __shfl_xor(v, 2, 64);
      v += __shfl_xor(v, 4, 64);
      v += __shfl_xor(v, 8, 64);
      zacc[jt][r] = v;
    }
    if (ln == 0){
      float4 o; o.x = zacc[jt][0]; o.y = zacc[jt][1]; o.z = zacc[jt][2]; o.w = zacc[jt][3];
      *(float4*)&part[((size_t)(b*NT_ + tile))*D_ + jb + jt*16 + q*4] = o;
    }
  }
}

// ---------------- fused tail: one block per batch, 512 threads, 5 GEMV phases ----------------
// u = (1/sum e) * sum_tl part[tl];  u2 = W2 u + b2;  z = Vw u2 + vb;
// h = gelu(Pw1 z + pb1);  out = Pw2 h + pb2
__global__ __launch_bounds__(512)
void k_tail(const float* __restrict__ part, const float* __restrict__ esum,
            const float* __restrict__ w2,  const float* __restrict__ b2x,
            const float* __restrict__ vw,  const float* __restrict__ vb,
            const float* __restrict__ pw1, const float* __restrict__ pb1,
            const float* __restrict__ pw2, const float* __restrict__ pb2,
            float* __restrict__ out){
  const int b = blockIdx.x, t = threadIdx.x;
  __shared__ float va[D_], vbuf[D_];
  __shared__ float sinv;

  if (t < 64){
    float p = wsum64(esum[b*NT_ + t]);
    if (t == 0) sinv = 1.0f / p;
  }
  // u: col t (reduce over 64 tiles; coalesced across t)
  float s = 0.f;
  {
    const float* pb_ = part + (size_t)b*NT_*D_ + t;
    #pragma unroll 8
    for (int tl = 0; tl < NT_; ++tl) s += pb_[tl*D_];
  }
  __syncthreads();               // sinv visible
  va[t] = s * sinv;
  __syncthreads();               // va = u ready

  // u2 = W2 u + b2 (row t)
  float d1;
  {
    const float4* rw = (const float4*)(w2 + (size_t)t*D_);
    float a0 = 0.f, a1 = 0.f;
    #pragma unroll 4
    for (int kk = 0; kk < 128; kk += 2){
      float4 h0 = *(const float4*)&va[kk*4];     float4 w0 = rw[kk];
      float4 h1 = *(const float4*)&va[kk*4+4];   float4 w1 = rw[kk+1];
      a0 += w0.x*h0.x + w0.y*h0.y + w0.z*h0.z + w0.w*h0.w;
      a1 += w1.x*h1.x + w1.y*h1.y + w1.z*h1.z + w1.w*h1.w;
    }
    d1 = a0 + a1 + b2x[t];
  }
  vbuf[t] = d1;
  __syncthreads();               // vbuf = u2 ready; va reads done

  // z = Vw u2 + vb (row t)
  float d2;
  {
    const float4* rw = (const float4*)(vw + (size_t)t*D_);
    float a0 = 0.f, a1 = 0.f;
    #pragma unroll 4
    for (int kk = 0; kk < 128; kk += 2){
      float4 h0 = *(const float4*)&vbuf[kk*4];   float4 w0 = rw[kk];
      float4 h1 = *(const float4*)&vbuf[kk*4+4]; float4 w1 = rw[kk+1];
      a0 += w0.x*h0.x + w0.y*h0.y + w0.z*h0.z + w0.w*h0.w;
      a1 += w1.x*h1.x + w1.y*h1.y + w1.z*h1.z + w1.w*h1.w;
    }
    d2 = a0 + a1 + vb[t];
  }
  va[t] = d2;
  __syncthreads();               // va = z ready; vbuf reads done

  // h = gelu(Pw1 z + pb1) (row t)
  float d3;
  {
    const float4* rw = (const float4*)(pw1 + (size_t)t*D_);
    float a0 = 0.f, a1 = 0.f;
    #pragma unroll 4
    for (int kk = 0; kk < 128; kk += 2){
      float4 h0 = *(const float4*)&va[kk*4];     float4 w0 = rw[kk];
      float4 h1 = *(const float4*)&va[kk*4+4];   float4 w1 = rw[kk+1];
      a0 += w0.x*h0.x + w0.y*h0.y + w0.z*h0.z + w0.w*h0.w;
      a1 += w1.x*h1.x + w1.y*h1.y + w1.z*h1.z + w1.w*h1.w;
    }
    d3 = gelu_f(a0 + a1 + pb1[t]);
  }
  vbuf[t] = d3;
  __syncthreads();               // vbuf = h ready; va reads done

  // out = Pw2 h + pb2 (rows t and 512+t)
  #pragma unroll
  for (int half = 0; half < 2; ++half){
    const int c = half*512 + t;
    if (c < NC_){
      const float4* rw = (const float4*)(pw2 + (size_t)c*D_);
      float a0 = 0.f, a1 = 0.f;
      #pragma unroll 4
      for (int kk = 0; kk < 128; kk += 2){
        float4 h0 = *(const float4*)&vbuf[kk*4];   float4 w0 = rw[kk];
        float4 h1 = *(const float4*)&vbuf[kk*4+4]; float4 w1 = rw[kk+1];
        a0 += w0.x*h0.x + w0.y*h0.y + w0.z*h0.z + w0.w*h0.w;
        a1 += w1.x*h1.x + w1.y*h1.y + w1.z*h1.z + w1.w*h1.w;
      }
      out[(size_t)b*NC_ + c] = a0 + a1 + pb2[c];
    }
  }
}

extern "C" void kernel_launch(void* const* d_in, const int* in_sizes, int n_in,
                              void* d_out, int out_size, void* d_ws, size_t ws_size,
                              hipStream_t stream) {
  (void)in_sizes; (void)n_in; (void)out_size; (void)ws_size;
  const float* x_items  = (const float*)d_in[0];
  const float* x_query  = (const float*)d_in[1];
  const float* psi_x_w1 = (const float*)d_in[2];
  const float* psi_x_b1 = (const float*)d_in[3];
  const float* psi_x_w2 = (const float*)d_in[4];
  const float* psi_x_b2 = (const float*)d_in[5];
  const float* psi_q_w1 = (const float*)d_in[6];
  const float* psi_q_b1 = (const float*)d_in[7];
  const float* psi_q_w2 = (const float*)d_in[8];
  const float* psi_q_b2 = (const float*)d_in[9];
  const float* q_w      = (const float*)d_in[10];
  const float* q_b      = (const float*)d_in[11];
  const float* k_w      = (const float*)d_in[12];
  // k_b (d_in[13]) unused: constant score shift cancels in softmax
  const float* v_w      = (const float*)d_in[14];
  const float* v_b      = (const float*)d_in[15];
  const float* phi_w1   = (const float*)d_in[16];
  const float* phi_b1   = (const float*)d_in[17];
  const float* phi_w2   = (const float*)d_in[18];
  const float* phi_b2   = (const float*)d_in[19];
  float* out = (float*)d_out;

  char* ws = (char*)d_ws;
  unsigned short* w1p = (unsigned short*)(ws);                 // 131072
  float* qkw2 = (float*)(ws + 131072);                         // 65536
  float* part = (float*)(ws + 196608);                         // 4194304
  float* esum = (float*)(ws + 4390912);                        // 8192

  hipLaunchKernelGGL(k_prep, dim3(256), dim3(256), 0, stream,
                     psi_x_w1, w1p);
  hipLaunchKernelGGL(k_qa, dim3(32), dim3(512), 0, stream,
                     x_query, psi_q_w1, psi_q_b1, psi_q_w2, psi_q_b2,
                     q_w, q_b, k_w, psi_x_w2, qkw2);
  hipLaunchKernelGGL(k_main, dim3(NT_, B_), dim3(512), 0, stream,
                     x_items, w1p, psi_x_b1, qkw2, part, esum);
  hipLaunchKernelGGL(k_tail, dim3(32), dim3(512), 0, stream,
                     part, esum, psi_x_w2, psi_x_b2, v_w, v_b,
                     phi_w1, phi_b1, phi_w2, phi_b2, out);
}

// Round 4
// 533.635 us; speedup vs baseline: 1.2339x; 1.0569x over previous
//
#include <hip/hip_runtime.h>
#include <hip/hip_bf16.h>

#define B_ 32
#define N_ 8192
#define DI_ 128
#define D_ 512
#define NC_ 1000
#define TN_ 128          // items per output tile (per block)
#define SN_ 32           // items per sub-tile
#define NSUB_ 4          // sub-tiles per block
#define NT_ 64           // tiles = N_/TN_
#define XROW_ 136        // x_lds row stride in shorts (pad +8)

typedef short s8v __attribute__((ext_vector_type(8)));
typedef float f4v __attribute__((ext_vector_type(4)));

__device__ __forceinline__ unsigned short f2bf(float f){
  union { float f; unsigned u; } c; c.f = f;
  unsigned r = c.u + 0x7fffu + ((c.u >> 16) & 1u);
  return (unsigned short)(r >> 16);
}

// hardware v_cvt_pk_bf16_f32: 2 floats -> packed bf16 (RNE), a in low 16
__device__ __forceinline__ unsigned pk2bf(float a, float b){
  float2 f; f.x = a; f.y = b;
  __hip_bfloat162 h = __float22bfloat162_rn(f);
  union { __hip_bfloat162 h; unsigned u; } c; c.h = h;
  return c.u;
}

// exact GELU: 0.5x(1+erf(x/sqrt2)); Abramowitz-Stegun 7.1.26, |err| <= 1.5e-7
__device__ __forceinline__ float gelu_f(float x){
  float ax = fabsf(x) * 0.70710678118654752f;
  float t = __builtin_amdgcn_rcpf(1.0f + 0.3275911f * ax);
  float poly = ((((1.061405429f*t - 1.453152027f)*t + 1.421413741f)*t
                 - 0.284496736f)*t + 0.254829592f)*t;
  float e = __expf(-ax*ax);
  float erf_ax = 1.0f - poly*e;
  erf_ax = (x >= 0.0f) ? erf_ax : -erf_ax;
  return 0.5f * x * (1.0f + erf_ax);
}

__device__ __forceinline__ float wsum64(float v){
  #pragma unroll
  for (int off = 32; off; off >>= 1) v += __shfl_xor(v, off, 64);
  return v;
}

// ---------------- fused prep + query chain: grid 160 x 512 ----------------
// blocks 0..127 : pack psi_x w1 to bf16 MFMA fragment order (128*512 = D_*DI_ elems)
// blocks 128..159: per-batch query chain:
//   h1q = gelu(xq*w1q + b1q); h2 = W2q h1q + b2q; qv = Qw h2 + qb;
//   qk[i] = scale * sum_d qv[d] Kw[d,i]; qkw2[k] = sum_i qk[i] W2[i,k]
__global__ __launch_bounds__(512)
void k_pq(const float* __restrict__ w1, unsigned short* __restrict__ w1p,
          const float* __restrict__ xq,
          const float* __restrict__ w1q, const float* __restrict__ b1q,
          const float* __restrict__ w2q, const float* __restrict__ b2q,
          const float* __restrict__ qw,  const float* __restrict__ qb,
          const float* __restrict__ kw,  const float* __restrict__ w2,
          float* __restrict__ qkw2g){
  const int t = threadIdx.x;
  if (blockIdx.x < 128){
    // ---- prep ----
    const int i = blockIdx.x * 512 + t;          // < 65536 = D_*DI_
    const int j = i / DI_, kc = i % DI_;
    const int kk = kc >> 5, q = (kc >> 3) & 3, s = kc & 7;
    w1p[((kk*D_ + j)*4 + q)*8 + s] = f2bf(w1[i]);
    return;
  }
  const int b = blockIdx.x - 128;
  __shared__ float va[D_], vb_[D_];
  // A: h1q
  va[t] = gelu_f(xq[b] * w1q[t] + b1q[t]);
  __syncthreads();
  // B: h2 (row per thread, 4 chains x unroll 8)
  {
    const float4* rw = (const float4*)(w2q + (size_t)t*D_);
    float a0=0.f, a1=0.f, a2=0.f, a3=0.f;
    #pragma unroll 8
    for (int kk = 0; kk < 128; kk += 4){
      float4 h0 = *(const float4*)&va[kk*4];      float4 w0 = rw[kk];
      float4 h1 = *(const float4*)&va[kk*4+4];    float4 wv1 = rw[kk+1];
      float4 h2 = *(const float4*)&va[kk*4+8];    float4 w2v = rw[kk+2];
      float4 h3 = *(const float4*)&va[kk*4+12];   float4 w3 = rw[kk+3];
      a0 += w0.x*h0.x + w0.y*h0.y + w0.z*h0.z + w0.w*h0.w;
      a1 += wv1.x*h1.x + wv1.y*h1.y + wv1.z*h1.z + wv1.w*h1.w;
      a2 += w2v.x*h2.x + w2v.y*h2.y + w2v.z*h2.z + w2v.w*h2.w;
      a3 += w3.x*h3.x + w3.y*h3.y + w3.z*h3.z + w3.w*h3.w;
    }
    vb_[t] = (a0+a1)+(a2+a3) + b2q[t];
  }
  __syncthreads();
  // C: qv (row per thread)
  float qv;
  {
    const float4* rw = (const float4*)(qw + (size_t)t*D_);
    float a0=0.f, a1=0.f, a2=0.f, a3=0.f;
    #pragma unroll 8
    for (int kk = 0; kk < 128; kk += 4){
      float4 h0 = *(const float4*)&vb_[kk*4];     float4 w0 = rw[kk];
      float4 h1 = *(const float4*)&vb_[kk*4+4];   float4 wv1 = rw[kk+1];
      float4 h2 = *(const float4*)&vb_[kk*4+8];   float4 w2v = rw[kk+2];
      float4 h3 = *(const float4*)&vb_[kk*4+12];  float4 w3 = rw[kk+3];
      a0 += w0.x*h0.x + w0.y*h0.y + w0.z*h0.z + w0.w*h0.w;
      a1 += wv1.x*h1.x + wv1.y*h1.y + wv1.z*h1.z + wv1.w*h1.w;
      a2 += w2v.x*h2.x + w2v.y*h2.y + w2v.z*h2.z + w2v.w*h2.w;
      a3 += w3.x*h3.x + w3.y*h3.y + w3.z*h3.z + w3.w*h3.w;
    }
    qv = (a0+a1)+(a2+a3) + qb[t];
  }
  __syncthreads();
  va[t] = qv;
  __syncthreads();
  // D: qk (coalesced over t, 8-deep ILP)
  {
    float ac[8] = {0.f,0.f,0.f,0.f,0.f,0.f,0.f,0.f};
    for (int d = 0; d < D_; d += 8){
      #pragma unroll
      for (int j = 0; j < 8; ++j)
        ac[j] += va[d+j] * kw[(size_t)(d+j)*D_ + t];
    }
    vb_[t] = 0.04419417382415922f *
             (((ac[0]+ac[1])+(ac[2]+ac[3])) + ((ac[4]+ac[5])+(ac[6]+ac[7])));
  }
  __syncthreads();
  // E: qkw2 (coalesced over t, 8-deep ILP)
  {
    float ac[8] = {0.f,0.f,0.f,0.f,0.f,0.f,0.f,0.f};
    for (int i = 0; i < D_; i += 8){
      #pragma unroll
      for (int j = 0; j < 8; ++j)
        ac[j] += vb_[i+j] * w2[(size_t)(i+j)*D_ + t];
    }
    qkw2g[b*D_ + t] = ((ac[0]+ac[1])+(ac[2]+ac[3])) + ((ac[4]+ac[5])+(ac[6]+ac[7]));
  }
}

// ---------------- main: GEMM1 + gelu + score(qkw2.h1) + weighted hbar accumulate ----------------
// GEMM2 eliminated algebraically: u = W2 @ (sum e*h1)/sum(e) + b2, applied per batch in k_tail2.
// launch_bounds(512,2): 256-reg cap; natural allocation ~156 total regs -> no spill. (FROZEN from r3.)
__global__ __launch_bounds__(512, 2)
void k_main(const float* __restrict__ x,                 // [B,N,DI]
            const unsigned short* __restrict__ w1p,      // packed bf16
            const float* __restrict__ b1,
            const float* __restrict__ qkw2,              // [B,D]
            float* __restrict__ part,                    // [B,NT,D] : sum e*h1 partials
            float* __restrict__ esum){                   // [B,NT]
  const int tile = blockIdx.x;       // 0..63
  const int b = blockIdx.y;          // 0..31
  const int t = threadIdx.x;         // 0..511
  const int lane = t & 63;
  const int wid = t >> 6;            // 0..7
  const int ln = lane & 15;
  const int q  = lane >> 4;          // 0..3

  __shared__ unsigned short x_lds[2][SN_ * XROW_];  // 2 x 8704 B
  __shared__ float s_ws[8][SN_];                    // 1024 B
  __shared__ float e_lds[SN_];                      // 128 B
  __shared__ float sb1[D_];                         // 2048 B
  __shared__ float sq2[D_];                         // 2048 B

  const int jb = wid * 64;              // this wave's 64-col j block
  const unsigned short* w1base = w1p + (jb + ln)*32 + q*8;
  const float* xbase = x + ((size_t)b * N_ + tile * TN_) * DI_;

  // invariants to LDS + stage sub 0
  sb1[t] = b1[t];
  sq2[t] = qkw2[b*D_ + t];
  {
    const float4* x4 = (const float4*)xbase;
    #pragma unroll
    for (int i = 0; i < 2; ++i){
      const int f = i*512 + t;            // 1024 float4 per sub-tile
      float4 v = x4[f];
      const int m = f >> 5;
      const int k = (f & 31) << 2;
      uint2 pk;
      pk.x = pk2bf(v.x, v.y);
      pk.y = pk2bf(v.z, v.w);
      *(uint2*)&x_lds[0][m*XROW_ + k] = pk;
    }
  }
  __syncthreads();

  f4v zacc[4];
  #pragma unroll
  for (int i = 0; i < 4; ++i) zacc[i] = (f4v){0.f,0.f,0.f,0.f};
  float etot = 0.f;

  for (int s = 0; s < NSUB_; ++s){
    const unsigned short* xb = x_lds[s & 1];

    f4v acc[8];
    #pragma unroll
    for (int i = 0; i < 8; ++i) acc[i] = (f4v){0.f,0.f,0.f,0.f};

    // ---- GEMM1: h1^T[j,m] = sum_k w1[j,k] * x[m,k] ----
    #pragma unroll
    for (int kk = 0; kk < 4; ++kk){
      const int k = kk*32 + q*8;
      s8v aw[4];
      #pragma unroll
      for (int jt = 0; jt < 4; ++jt)
        aw[jt] = *(const s8v*)(w1base + kk*(D_*32) + jt*(16*32));
      s8v bx[2];
      #pragma unroll
      for (int mi = 0; mi < 2; ++mi)
        bx[mi] = *(const s8v*)&xb[(mi*16 + ln)*XROW_ + k];
      #pragma unroll
      for (int jt = 0; jt < 4; ++jt)
        #pragma unroll
        for (int mi = 0; mi < 2; ++mi)
          acc[jt*2+mi] = __builtin_amdgcn_mfma_f32_16x16x32_bf16(aw[jt], bx[mi], acc[jt*2+mi], 0,0,0);
    }

    // ---- prefetch next sub-tile into regs (HBM latency hides under gelu/score) ----
    float4 pv0, pv1;
    if (s + 1 < NSUB_){
      const float4* x4 = (const float4*)(xbase + (size_t)(s+1)*SN_*DI_);
      pv0 = x4[t];
      pv1 = x4[512 + t];
    }

    // ---- bias + exact GELU (in place) + score partial over this wave's 64 j ----
    float sp0 = 0.f, sp1 = 0.f;
    #pragma unroll
    for (int jt = 0; jt < 4; ++jt){
      const f4v bv = *(const f4v*)&sb1[jb + jt*16 + q*4];
      const f4v qv = *(const f4v*)&sq2[jb + jt*16 + q*4];
      #pragma unroll
      for (int mi = 0; mi < 2; ++mi){
        f4v a = acc[jt*2+mi];
        a[0] = gelu_f(a[0] + bv[0]);
        a[1] = gelu_f(a[1] + bv[1]);
        a[2] = gelu_f(a[2] + bv[2]);
        a[3] = gelu_f(a[3] + bv[3]);
        acc[jt*2+mi] = a;
        const float d = qv[0]*a[0] + qv[1]*a[1] + qv[2]*a[2] + qv[3]*a[3];
        if (mi == 0) sp0 += d; else sp1 += d;
      }
    }
    // reduce over q lanes (xor 16,32): full-j partial per m = mi*16+ln
    sp0 += __shfl_xor(sp0, 16, 64); sp0 += __shfl_xor(sp0, 32, 64);
    sp1 += __shfl_xor(sp1, 16, 64); sp1 += __shfl_xor(sp1, 32, 64);
    if (q == 0) s_ws[wid][lane] = sp0;        // lane = ln      -> m = ln
    if (q == 1) s_ws[wid][lane] = sp1;        // lane = 16+ln   -> m = 16+ln

    // ---- write prefetched x to the other LDS buffer ----
    if (s + 1 < NSUB_){
      unsigned short* xn = &x_lds[(s+1) & 1][0];
      int f = t, m = f >> 5, k = (f & 31) << 2;
      uint2 pk;
      pk.x = pk2bf(pv0.x, pv0.y);
      pk.y = pk2bf(pv0.z, pv0.w);
      *(uint2*)&xn[m*XROW_ + k] = pk;
      f = 512 + t; m = f >> 5; k = (f & 31) << 2;
      pk.x = pk2bf(pv1.x, pv1.y);
      pk.y = pk2bf(pv1.z, pv1.w);
      *(uint2*)&xn[m*XROW_ + k] = pk;
    }
    __syncthreads();     // (A) scores complete, staging complete

    if (t < SN_){
      float sc = 0.f;
      #pragma unroll
      for (int w = 0; w < 8; ++w) sc += s_ws[w][t];
      e_lds[t] = __expf(sc);     // constant shift (qk.b2, k_b) cancels in softmax
    }
    __syncthreads();     // (B) e ready

    if (wid == 0){
      float v = (lane < SN_) ? e_lds[lane] : 0.f;
      etot += wsum64(v);
    }

    // ---- weighted hbar accumulate: zacc[j] += sum_m e[m]*h1[m,j] (per-lane mi part) ----
    {
      const float em0 = e_lds[ln];
      const float em1 = e_lds[16 + ln];
      #pragma unroll
      for (int jt = 0; jt < 4; ++jt){
        const f4v a0 = acc[jt*2+0];
        const f4v a1 = acc[jt*2+1];
        #pragma unroll
        for (int r = 0; r < 4; ++r)
          zacc[jt][r] += em0*a0[r] + em1*a1[r];
      }
    }
    // no barrier needed: next iter's e_lds write is after its own barrier (A)
  }

  if (t == 0) esum[b*NT_ + tile] = etot;

  // reduce zacc over ln lanes (same q => same j set), write 4x float4 per q-lane
  #pragma unroll
  for (int jt = 0; jt < 4; ++jt){
    #pragma unroll
    for (int r = 0; r < 4; ++r){
      float v = zacc[jt][r];
      v += __shfl_xor(v, 1, 64);
      v += __shfl_xor(v, 2, 64);
      v += __shfl_xor(v, 4, 64);
      v += __shfl_xor(v, 8, 64);
      zacc[jt][r] = v;
    }
    if (ln == 0){
      float4 o; o.x = zacc[jt][0]; o.y = zacc[jt][1]; o.z = zacc[jt][2]; o.w = zacc[jt][3];
      *(float4*)&part[((size_t)(b*NT_ + tile))*D_ + jb + jt*16 + q*4] = o;
    }
  }
}

// ---------------- wide fused tail: grid (32, 8) x 512 ----------------
// Each block REDUNDANTLY computes the shared serial prefix (u, u2, z, h) for its batch
// -- ~800K FMA + ~3.4 MB L2 reads per block (cheap, full-machine TLP) --
// then writes its own 125-column slice of out. 256 blocks total.
__global__ __launch_bounds__(512)
void k_tail2(const float* __restrict__ part, const float* __restrict__ esum,
             const float* __restrict__ w2,  const float* __restrict__ b2x,
             const float* __restrict__ vw,  const float* __restrict__ vb,
             const float* __restrict__ pw1, const float* __restrict__ pb1,
             const float* __restrict__ pw2, const float* __restrict__ pb2,
             float* __restrict__ out){
  const int b = blockIdx.x, sl = blockIdx.y, t = threadIdx.x;
  __shared__ float va[D_], vbuf[D_];
  __shared__ float sinv_s;

  if (t < 64){
    float p = wsum64(esum[b*NT_ + t]);
    if (t == 0) sinv_s = 1.0f / p;
  }
  // u: col t (reduce over 64 tiles; coalesced across t)
  float s = 0.f;
  {
    const float* pb_ = part + (size_t)b*NT_*D_ + t;
    #pragma unroll 8
    for (int tl = 0; tl < NT_; ++tl) s += pb_[tl*D_];
  }
  __syncthreads();               // sinv_s visible
  va[t] = s * sinv_s;
  __syncthreads();               // va = u ready

  // u2 = W2 u + b2 (row t)
  {
    const float4* rw = (const float4*)(w2 + (size_t)t*D_);
    float a0=0.f, a1=0.f, a2=0.f, a3=0.f;
    #pragma unroll 8
    for (int kk = 0; kk < 128; kk += 4){
      float4 h0 = *(const float4*)&va[kk*4];      float4 w0 = rw[kk];
      float4 h1 = *(const float4*)&va[kk*4+4];    float4 wv1 = rw[kk+1];
      float4 h2 = *(const float4*)&va[kk*4+8];    float4 w2v = rw[kk+2];
      float4 h3 = *(const float4*)&va[kk*4+12];   float4 w3 = rw[kk+3];
      a0 += w0.x*h0.x + w0.y*h0.y + w0.z*h0.z + w0.w*h0.w;
      a1 += wv1.x*h1.x + wv1.y*h1.y + wv1.z*h1.z + wv1.w*h1.w;
      a2 += w2v.x*h2.x + w2v.y*h2.y + w2v.z*h2.z + w2v.w*h2.w;
      a3 += w3.x*h3.x + w3.y*h3.y + w3.z*h3.z + w3.w*h3.w;
    }
    vbuf[t] = (a0+a1)+(a2+a3) + b2x[t];
  }
  __syncthreads();               // vbuf = u2 ready; va reads done

  // z = Vw u2 + vb (row t)
  {
    const float4* rw = (const float4*)(vw + (size_t)t*D_);
    float a0=0.f, a1=0.f, a2=0.f, a3=0.f;
    #pragma unroll 8
    for (int kk = 0; kk < 128; kk += 4){
      float4 h0 = *(const float4*)&vbuf[kk*4];    float4 w0 = rw[kk];
      float4 h1 = *(const float4*)&vbuf[kk*4+4];  float4 wv1 = rw[kk+1];
      float4 h2 = *(const float4*)&vbuf[kk*4+8];  float4 w2v = rw[kk+2];
      float4 h3 = *(const float4*)&vbuf[kk*4+12]; float4 w3 = rw[kk+3];
      a0 += w0.x*h0.x + w0.y*h0.y + w0.z*h0.z + w0.w*h0.w;
      a1 += wv1.x*h1.x + wv1.y*h1.y + wv1.z*h1.z + wv1.w*h1.w;
      a2 += w2v.x*h2.x + w2v.y*h2.y + w2v.z*h2.z + w2v.w*h2.w;
      a3 += w3.x*h3.x + w3.y*h3.y + w3.z*h3.z + w3.w*h3.w;
    }
    va[t] = (a0+a1)+(a2+a3) + vb[t];   // safe: va last read before previous barrier
  }
  __syncthreads();               // va = z ready

  // h = gelu(Pw1 z + pb1) (row t)
  {
    const float4* rw = (const float4*)(pw1 + (size_t)t*D_);
    float a0=0.f, a1=0.f, a2=0.f, a3=0.f;
    #pragma unroll 8
    for (int kk = 0; kk < 128; kk += 4){
      float4 h0 = *(const float4*)&va[kk*4];      float4 w0 = rw[kk];
      float4 h1 = *(const float4*)&va[kk*4+4];    float4 wv1 = rw[kk+1];
      float4 h2 = *(const float4*)&va[kk*4+8];    float4 w2v = rw[kk+2];
      float4 h3 = *(const float4*)&va[kk*4+12];   float4 w3 = rw[kk+3];
      a0 += w0.x*h0.x + w0.y*h0.y + w0.z*h0.z + w0.w*h0.w;
      a1 += wv1.x*h1.x + wv1.y*h1.y + wv1.z*h1.z + wv1.w*h1.w;
      a2 += w2v.x*h2.x + w2v.y*h2.y + w2v.z*h2.z + w2v.w*h2.w;
      a3 += w3.x*h3.x + w3.y*h3.y + w3.z*h3.z + w3.w*h3.w;
    }
    vbuf[t] = gelu_f((a0+a1)+(a2+a3) + pb1[t]);  // safe: vbuf last read before previous barrier
  }
  __syncthreads();               // vbuf = h ready

  // out slice: this block owns cols [sl*125, sl*125+125) ; 8*125 = 1000 = NC_
  if (t < 125){
    const int c = sl*125 + t;
    const float4* rw = (const float4*)(pw2 + (size_t)c*D_);
    float a0=0.f, a1=0.f, a2=0.f, a3=0.f;
    #pragma unroll 8
    for (int kk = 0; kk < 128; kk += 4){
      float4 h0 = *(const float4*)&vbuf[kk*4];    float4 w0 = rw[kk];
      float4 h1 = *(const float4*)&vbuf[kk*4+4];  float4 wv1 = rw[kk+1];
      float4 h2 = *(const float4*)&vbuf[kk*4+8];  float4 w2v = rw[kk+2];
      float4 h3 = *(const float4*)&vbuf[kk*4+12]; float4 w3 = rw[kk+3];
      a0 += w0.x*h0.x + w0.y*h0.y + w0.z*h0.z + w0.w*h0.w;
      a1 += wv1.x*h1.x + wv1.y*h1.y + wv1.z*h1.z + wv1.w*h1.w;
      a2 += w2v.x*h2.x + w2v.y*h2.y + w2v.z*h2.z + w2v.w*h2.w;
      a3 += w3.x*h3.x + w3.y*h3.y + w3.z*h3.z + w3.w*h3.w;
    }
    out[(size_t)b*NC_ + c] = (a0+a1)+(a2+a3) + pb2[c];
  }
}

extern "C" void kernel_launch(void* const* d_in, const int* in_sizes, int n_in,
                              void* d_out, int out_size, void* d_ws, size_t ws_size,
                              hipStream_t stream) {
  (void)in_sizes; (void)n_in; (void)out_size; (void)ws_size;
  const float* x_items  = (const float*)d_in[0];
  const float* x_query  = (const float*)d_in[1];
  const float* psi_x_w1 = (const float*)d_in[2];
  const float* psi_x_b1 = (const float*)d_in[3];
  const float* psi_x_w2 = (const float*)d_in[4];
  const float* psi_x_b2 = (const float*)d_in[5];
  const float* psi_q_w1 = (const float*)d_in[6];
  const float* psi_q_b1 = (const float*)d_in[7];
  const float* psi_q_w2 = (const float*)d_in[8];
  const float* psi_q_b2 = (const float*)d_in[9];
  const float* q_w      = (const float*)d_in[10];
  const float* q_b      = (const float*)d_in[11];
  const float* k_w      = (const float*)d_in[12];
  // k_b (d_in[13]) unused: constant score shift cancels in softmax
  const float* v_w      = (const float*)d_in[14];
  const float* v_b      = (const float*)d_in[15];
  const float* phi_w1   = (const float*)d_in[16];
  const float* phi_b1   = (const float*)d_in[17];
  const float* phi_w2   = (const float*)d_in[18];
  const float* phi_b2   = (const float*)d_in[19];
  float* out = (float*)d_out;

  char* ws = (char*)d_ws;
  unsigned short* w1p = (unsigned short*)(ws);                 // 131072
  float* qkw2 = (float*)(ws + 131072);                         // 65536
  float* part = (float*)(ws + 196608);                         // 4194304
  float* esum = (float*)(ws + 4390912);                        // 8192

  hipLaunchKernelGGL(k_pq, dim3(160), dim3(512), 0, stream,
                     psi_x_w1, w1p, x_query,
                     psi_q_w1, psi_q_b1, psi_q_w2, psi_q_b2,
                     q_w, q_b, k_w, psi_x_w2, qkw2);
  hipLaunchKernelGGL(k_main, dim3(NT_, B_), dim3(512), 0, stream,
                     x_items, w1p, psi_x_b1, qkw2, part, esum);
  hipLaunchKernelGGL(k_tail2, dim3(32, 8), dim3(512), 0, stream,
                     part, esum, psi_x_w2, psi_x_b2, v_w, v_b,
                     phi_w1, phi_b1, phi_w2, phi_b2, out);
}

// Round 5
// 457.790 us; speedup vs baseline: 1.4383x; 1.1657x over previous
//
#include <hip/hip_runtime.h>
#include <hip/hip_bf16.h>

#define B_ 32
#define N_ 8192
#define DI_ 128
#define D_ 512
#define NC_ 1000
#define TN_ 128          // items per output tile (per block)
#define SN_ 32           // items per sub-tile
#define NSUB_ 4          // sub-tiles per block
#define NT_ 64           // tiles = N_/TN_
#define XROW_ 136        // x_lds row stride in shorts (pad +8)

typedef short s8v __attribute__((ext_vector_type(8)));
typedef float f4v __attribute__((ext_vector_type(4)));

__device__ __forceinline__ unsigned short f2bf(float f){
  union { float f; unsigned u; } c; c.f = f;
  unsigned r = c.u + 0x7fffu + ((c.u >> 16) & 1u);
  return (unsigned short)(r >> 16);
}

// hardware v_cvt_pk_bf16_f32: 2 floats -> packed bf16 (RNE), a in low 16
__device__ __forceinline__ unsigned pk2bf(float a, float b){
  float2 f; f.x = a; f.y = b;
  __hip_bfloat162 h = __float22bfloat162_rn(f);
  union { __hip_bfloat162 h; unsigned u; } c; c.h = h;
  return c.u;
}

// exact GELU: 0.5x(1+erf(x/sqrt2)); Abramowitz-Stegun 7.1.26, |err| <= 1.5e-7
__device__ __forceinline__ float gelu_f(float x){
  float ax = fabsf(x) * 0.70710678118654752f;
  float t = __builtin_amdgcn_rcpf(1.0f + 0.3275911f * ax);
  float poly = ((((1.061405429f*t - 1.453152027f)*t + 1.421413741f)*t
                 - 0.284496736f)*t + 0.254829592f)*t;
  float e = __expf(-ax*ax);
  float erf_ax = 1.0f - poly*e;
  erf_ax = (x >= 0.0f) ? erf_ax : -erf_ax;
  return 0.5f * x * (1.0f + erf_ax);
}

__device__ __forceinline__ float wsum64(float v){
  #pragma unroll
  for (int off = 32; off; off >>= 1) v += __shfl_xor(v, off, 64);
  return v;
}

// ---------------- prep: w1 bf16 pack + transpose 6 tail/query weight matrices ----------------
// blocks 0..127  : pack psi_x w1 (D_*DI_ = 65536 elems)
// blocks 128..447: transpose 5 square 512x512 matrices (64 tiles of 64x64 each)
// blocks 448..575: transpose phi_w2 [1000][512] -> pw2T [512][1000] (16x8 tiles)
// Row-per-thread GEMVs have 2KB-stride lane access (4-8x sector amplification, r4 lesson);
// transposing once makes every tail GEMV lane-coalesced.
__global__ __launch_bounds__(512)
void k_prep2(const float* __restrict__ w1, unsigned short* __restrict__ w1p,
             const float* __restrict__ sw0, float* __restrict__ dt0,   // psi_x_w2 -> w2T
             const float* __restrict__ sw1, float* __restrict__ dt1,   // v_w     -> vwT
             const float* __restrict__ sw2, float* __restrict__ dt2,   // phi_w1  -> pw1T
             const float* __restrict__ sw3, float* __restrict__ dt3,   // psi_q_w2-> w2qT
             const float* __restrict__ sw4, float* __restrict__ dt4,   // q_w     -> qwT
             const float* __restrict__ pw2, float* __restrict__ pw2T){
  const int t = threadIdx.x;
  const int bid = blockIdx.x;
  if (bid < 128){
    const int i = bid*512 + t;                 // < 65536 = D_*DI_
    const int j = i / DI_, kc = i % DI_;
    const int kk = kc >> 5, q = (kc >> 3) & 3, s = kc & 7;
    w1p[((kk*D_ + j)*4 + q)*8 + s] = f2bf(w1[i]);
    return;
  }
  __shared__ float tile[64][65];               // +1 pad: 2-way LDS aliasing only (free)
  const int r0 = t >> 6;                       // 0..7
  const int c  = t & 63;
  if (bid < 448){
    const int id = bid - 128;
    const int mi = id >> 6;                    // matrix 0..4
    const int tt = id & 63;
    const int to = tt >> 3, tk = tt & 7;       // row-tile (out), col-tile (in)
    const float* src = mi==0?sw0: mi==1?sw1: mi==2?sw2: mi==3?sw3: sw4;
    float*       dst = mi==0?dt0: mi==1?dt1: mi==2?dt2: mi==3?dt3: dt4;
    #pragma unroll
    for (int i = 0; i < 8; ++i){
      const int r = r0 + i*8;
      tile[r][c] = src[(size_t)(to*64 + r)*D_ + tk*64 + c];
    }
    __syncthreads();
    #pragma unroll
    for (int i = 0; i < 8; ++i){
      const int r = r0 + i*8;
      dst[(size_t)(tk*64 + r)*D_ + to*64 + c] = tile[c][r];
    }
  } else {
    const int id = bid - 448;                  // 0..127
    const int tr = id >> 3, tk = id & 7;       // tr: 1000-row tiles (16), tk: 512-col tiles (8)
    #pragma unroll
    for (int i = 0; i < 8; ++i){
      const int r = r0 + i*8;
      const int ro = tr*64 + r;
      tile[r][c] = (ro < NC_) ? pw2[(size_t)ro*D_ + tk*64 + c] : 0.f;
    }
    __syncthreads();
    #pragma unroll
    for (int i = 0; i < 8; ++i){
      const int r = r0 + i*8;
      const int co = tr*64 + c;
      if (co < NC_)
        pw2T[(size_t)(tk*64 + r)*NC_ + co] = tile[c][r];
    }
  }
}

// ---------------- query chain: 32 blocks x 512, ALL phases lane-coalesced ----------------
// h1q = gelu(xq*w1q + b1q); h2 = W2q h1q + b2q (via w2qT); qv = Qw h2 + qb (via qwT);
// qk[i] = scale * sum_d qv[d] Kw[d,i]; qkw2[k] = sum_j qk[j] W2[j,k]
__global__ __launch_bounds__(512)
void k_q(const float* __restrict__ xq,
         const float* __restrict__ w1q,  const float* __restrict__ b1q,
         const float* __restrict__ w2qT, const float* __restrict__ b2q,
         const float* __restrict__ qwT,  const float* __restrict__ qb,
         const float* __restrict__ kw,   const float* __restrict__ w2,
         float* __restrict__ qkw2g){
  const int b = blockIdx.x, t = threadIdx.x;
  __shared__ float va[D_], vb_[D_];
  va[t] = gelu_f(xq[b] * w1q[t] + b1q[t]);
  __syncthreads();
  // B: h2[t] = sum_k w2qT[k][t] * h1q[k]
  {
    float ac[8] = {0.f,0.f,0.f,0.f,0.f,0.f,0.f,0.f};
    for (int k = 0; k < D_; k += 8){
      #pragma unroll
      for (int j = 0; j < 8; ++j)
        ac[j] += w2qT[(size_t)(k+j)*D_ + t] * va[k+j];
    }
    vb_[t] = (((ac[0]+ac[1])+(ac[2]+ac[3])) + ((ac[4]+ac[5])+(ac[6]+ac[7]))) + b2q[t];
  }
  __syncthreads();
  // C: qv[t] = sum_k qwT[k][t] * h2[k]   (va overwrite safe: va last read before B's barrier)
  {
    float ac[8] = {0.f,0.f,0.f,0.f,0.f,0.f,0.f,0.f};
    for (int k = 0; k < D_; k += 8){
      #pragma unroll
      for (int j = 0; j < 8; ++j)
        ac[j] += qwT[(size_t)(k+j)*D_ + t] * vb_[k+j];
    }
    va[t] = (((ac[0]+ac[1])+(ac[2]+ac[3])) + ((ac[4]+ac[5])+(ac[6]+ac[7]))) + qb[t];
  }
  __syncthreads();
  // D: qk[t] = scale * sum_d qv[d] * kw[d][t]
  {
    float ac[8] = {0.f,0.f,0.f,0.f,0.f,0.f,0.f,0.f};
    for (int d = 0; d < D_; d += 8){
      #pragma unroll
      for (int j = 0; j < 8; ++j)
        ac[j] += kw[(size_t)(d+j)*D_ + t] * va[d+j];
    }
    vb_[t] = 0.04419417382415922f *
             ((((ac[0]+ac[1])+(ac[2]+ac[3])) + ((ac[4]+ac[5])+(ac[6]+ac[7]))));
  }
  __syncthreads();
  // E: qkw2[t] = sum_j qk[j] * w2[j][t]
  {
    float ac[8] = {0.f,0.f,0.f,0.f,0.f,0.f,0.f,0.f};
    for (int j0 = 0; j0 < D_; j0 += 8){
      #pragma unroll
      for (int j = 0; j < 8; ++j)
        ac[j] += w2[(size_t)(j0+j)*D_ + t] * vb_[j0+j];
    }
    qkw2g[b*D_ + t] = (((ac[0]+ac[1])+(ac[2]+ac[3])) + ((ac[4]+ac[5])+(ac[6]+ac[7])));
  }
}

// ---------------- main: GEMM1 + gelu + score(qkw2.h1) + weighted hbar accumulate ----------------
// GEMM2 eliminated algebraically: u = W2 @ (sum e*h1)/sum(e) + b2, applied per batch in k_tail3.
// launch_bounds(512,2): 256-reg cap; natural allocation ~156 total regs -> no spill. (FROZEN from r3.)
__global__ __launch_bounds__(512, 2)
void k_main(const float* __restrict__ x,                 // [B,N,DI]
            const unsigned short* __restrict__ w1p,      // packed bf16
            const float* __restrict__ b1,
            const float* __restrict__ qkw2,              // [B,D]
            float* __restrict__ part,                    // [B,NT,D] : sum e*h1 partials
            float* __restrict__ esum){                   // [B,NT]
  const int tile = blockIdx.x;       // 0..63
  const int b = blockIdx.y;          // 0..31
  const int t = threadIdx.x;         // 0..511
  const int lane = t & 63;
  const int wid = t >> 6;            // 0..7
  const int ln = lane & 15;
  const int q  = lane >> 4;          // 0..3

  __shared__ unsigned short x_lds[2][SN_ * XROW_];  // 2 x 8704 B
  __shared__ float s_ws[8][SN_];                    // 1024 B
  __shared__ float e_lds[SN_];                      // 128 B
  __shared__ float sb1[D_];                         // 2048 B
  __shared__ float sq2[D_];                         // 2048 B

  const int jb = wid * 64;              // this wave's 64-col j block
  const unsigned short* w1base = w1p + (jb + ln)*32 + q*8;
  const float* xbase = x + ((size_t)b * N_ + tile * TN_) * DI_;

  // invariants to LDS + stage sub 0
  sb1[t] = b1[t];
  sq2[t] = qkw2[b*D_ + t];
  {
    const float4* x4 = (const float4*)xbase;
    #pragma unroll
    for (int i = 0; i < 2; ++i){
      const int f = i*512 + t;            // 1024 float4 per sub-tile
      float4 v = x4[f];
      const int m = f >> 5;
      const int k = (f & 31) << 2;
      uint2 pk;
      pk.x = pk2bf(v.x, v.y);
      pk.y = pk2bf(v.z, v.w);
      *(uint2*)&x_lds[0][m*XROW_ + k] = pk;
    }
  }
  __syncthreads();

  f4v zacc[4];
  #pragma unroll
  for (int i = 0; i < 4; ++i) zacc[i] = (f4v){0.f,0.f,0.f,0.f};
  float etot = 0.f;

  for (int s = 0; s < NSUB_; ++s){
    const unsigned short* xb = x_lds[s & 1];

    f4v acc[8];
    #pragma unroll
    for (int i = 0; i < 8; ++i) acc[i] = (f4v){0.f,0.f,0.f,0.f};

    // ---- GEMM1: h1^T[j,m] = sum_k w1[j,k] * x[m,k] ----
    #pragma unroll
    for (int kk = 0; kk < 4; ++kk){
      const int k = kk*32 + q*8;
      s8v aw[4];
      #pragma unroll
      for (int jt = 0; jt < 4; ++jt)
        aw[jt] = *(const s8v*)(w1base + kk*(D_*32) + jt*(16*32));
      s8v bx[2];
      #pragma unroll
      for (int mi = 0; mi < 2; ++mi)
        bx[mi] = *(const s8v*)&xb[(mi*16 + ln)*XROW_ + k];
      #pragma unroll
      for (int jt = 0; jt < 4; ++jt)
        #pragma unroll
        for (int mi = 0; mi < 2; ++mi)
          acc[jt*2+mi] = __builtin_amdgcn_mfma_f32_16x16x32_bf16(aw[jt], bx[mi], acc[jt*2+mi], 0,0,0);
    }

    // ---- prefetch next sub-tile into regs (HBM latency hides under gelu/score) ----
    float4 pv0, pv1;
    if (s + 1 < NSUB_){
      const float4* x4 = (const float4*)(xbase + (size_t)(s+1)*SN_*DI_);
      pv0 = x4[t];
      pv1 = x4[512 + t];
    }

    // ---- bias + exact GELU (in place) + score partial over this wave's 64 j ----
    float sp0 = 0.f, sp1 = 0.f;
    #pragma unroll
    for (int jt = 0; jt < 4; ++jt){
      const f4v bv = *(const f4v*)&sb1[jb + jt*16 + q*4];
      const f4v qv = *(const f4v*)&sq2[jb + jt*16 + q*4];
      #pragma unroll
      for (int mi = 0; mi < 2; ++mi){
        f4v a = acc[jt*2+mi];
        a[0] = gelu_f(a[0] + bv[0]);
        a[1] = gelu_f(a[1] + bv[1]);
        a[2] = gelu_f(a[2] + bv[2]);
        a[3] = gelu_f(a[3] + bv[3]);
        acc[jt*2+mi] = a;
        const float d = qv[0]*a[0] + qv[1]*a[1] + qv[2]*a[2] + qv[3]*a[3];
        if (mi == 0) sp0 += d; else sp1 += d;
      }
    }
    // reduce over q lanes (xor 16,32): full-j partial per m = mi*16+ln
    sp0 += __shfl_xor(sp0, 16, 64); sp0 += __shfl_xor(sp0, 32, 64);
    sp1 += __shfl_xor(sp1, 16, 64); sp1 += __shfl_xor(sp1, 32, 64);
    if (q == 0) s_ws[wid][lane] = sp0;        // lane = ln      -> m = ln
    if (q == 1) s_ws[wid][lane] = sp1;        // lane = 16+ln   -> m = 16+ln

    // ---- write prefetched x to the other LDS buffer ----
    if (s + 1 < NSUB_){
      unsigned short* xn = &x_lds[(s+1) & 1][0];
      int f = t, m = f >> 5, k = (f & 31) << 2;
      uint2 pk;
      pk.x = pk2bf(pv0.x, pv0.y);
      pk.y = pk2bf(pv0.z, pv0.w);
      *(uint2*)&xn[m*XROW_ + k] = pk;
      f = 512 + t; m = f >> 5; k = (f & 31) << 2;
      pk.x = pk2bf(pv1.x, pv1.y);
      pk.y = pk2bf(pv1.z, pv1.w);
      *(uint2*)&xn[m*XROW_ + k] = pk;
    }
    __syncthreads();     // (A) scores complete, staging complete

    if (t < SN_){
      float sc = 0.f;
      #pragma unroll
      for (int w = 0; w < 8; ++w) sc += s_ws[w][t];
      e_lds[t] = __expf(sc);     // constant shift (qk.b2, k_b) cancels in softmax
    }
    __syncthreads();     // (B) e ready

    if (wid == 0){
      float v = (lane < SN_) ? e_lds[lane] : 0.f;
      etot += wsum64(v);
    }

    // ---- weighted hbar accumulate: zacc[j] += sum_m e[m]*h1[m,j] (per-lane mi part) ----
    {
      const float em0 = e_lds[ln];
      const float em1 = e_lds[16 + ln];
      #pragma unroll
      for (int jt = 0; jt < 4; ++jt){
        const f4v a0 = acc[jt*2+0];
        const f4v a1 = acc[jt*2+1];
        #pragma unroll
        for (int r = 0; r < 4; ++r)
          zacc[jt][r] += em0*a0[r] + em1*a1[r];
      }
    }
    // no barrier needed: next iter's e_lds write is after its own barrier (A)
  }

  if (t == 0) esum[b*NT_ + tile] = etot;

  // reduce zacc over ln lanes (same q => same j set), write 4x float4 per q-lane
  #pragma unroll
  for (int jt = 0; jt < 4; ++jt){
    #pragma unroll
    for (int r = 0; r < 4; ++r){
      float v = zacc[jt][r];
      v += __shfl_xor(v, 1, 64);
      v += __shfl_xor(v, 2, 64);
      v += __shfl_xor(v, 4, 64);
      v += __shfl_xor(v, 8, 64);
      zacc[jt][r] = v;
    }
    if (ln == 0){
      float4 o; o.x = zacc[jt][0]; o.y = zacc[jt][1]; o.z = zacc[jt][2]; o.w = zacc[jt][3];
      *(float4*)&part[((size_t)(b*NT_ + tile))*D_ + jb + jt*16 + q*4] = o;
    }
  }
}

// ---------------- fused tail: 32 blocks x 512, ALL phases lane-coalesced via transposed W ----------------
// u = (1/sum e) * sum_tl part[tl];  u2 = W2 u + b2 (w2T);  z = Vw u2 + vb (vwT);
// h = gelu(Pw1 z + pb1) (pw1T);  out = Pw2 h + pb2 (pw2T)
__global__ __launch_bounds__(512)
void k_tail3(const float* __restrict__ part, const float* __restrict__ esum,
             const float* __restrict__ w2T,  const float* __restrict__ b2x,
             const float* __restrict__ vwT,  const float* __restrict__ vb,
             const float* __restrict__ pw1T, const float* __restrict__ pb1,
             const float* __restrict__ pw2T, const float* __restrict__ pb2,
             float* __restrict__ out){
  const int b = blockIdx.x, t = threadIdx.x;
  __shared__ float va[D_], vb_[D_];
  __shared__ float sinv_s;

  if (t < 64){
    float p = wsum64(esum[b*NT_ + t]);
    if (t == 0) sinv_s = 1.0f / p;
  }
  // u: col t (reduce over 64 tiles; coalesced across t)
  float s = 0.f;
  {
    const float* pb_ = part + (size_t)b*NT_*D_ + t;
    #pragma unroll 8
    for (int tl = 0; tl < NT_; ++tl) s += pb_[tl*D_];
  }
  __syncthreads();               // sinv_s visible
  va[t] = s * sinv_s;
  __syncthreads();               // va = u ready

  // u2[t] = sum_k w2T[k][t] * u[k] + b2x[t]
  {
    float ac[8] = {0.f,0.f,0.f,0.f,0.f,0.f,0.f,0.f};
    for (int k = 0; k < D_; k += 8){
      #pragma unroll
      for (int j = 0; j < 8; ++j)
        ac[j] += w2T[(size_t)(k+j)*D_ + t] * va[k+j];
    }
    vb_[t] = (((ac[0]+ac[1])+(ac[2]+ac[3])) + ((ac[4]+ac[5])+(ac[6]+ac[7]))) + b2x[t];
  }
  __syncthreads();               // vb_ = u2 ready

  // z[t] = sum_k vwT[k][t] * u2[k] + vb[t]   (va overwrite safe)
  {
    float ac[8] = {0.f,0.f,0.f,0.f,0.f,0.f,0.f,0.f};
    for (int k = 0; k < D_; k += 8){
      #pragma unroll
      for (int j = 0; j < 8; ++j)
        ac[j] += vwT[(size_t)(k+j)*D_ + t] * vb_[k+j];
    }
    va[t] = (((ac[0]+ac[1])+(ac[2]+ac[3])) + ((ac[4]+ac[5])+(ac[6]+ac[7]))) + vb[t];
  }
  __syncthreads();               // va = z ready

  // h[t] = gelu(sum_k pw1T[k][t] * z[k] + pb1[t])
  {
    float ac[8] = {0.f,0.f,0.f,0.f,0.f,0.f,0.f,0.f};
    for (int k = 0; k < D_; k += 8){
      #pragma unroll
      for (int j = 0; j < 8; ++j)
        ac[j] += pw1T[(size_t)(k+j)*D_ + t] * va[k+j];
    }
    vb_[t] = gelu_f((((ac[0]+ac[1])+(ac[2]+ac[3])) + ((ac[4]+ac[5])+(ac[6]+ac[7]))) + pb1[t]);
  }
  __syncthreads();               // vb_ = h ready

  // out[c] for c = t and c = 512+t (c<1000): sum_k pw2T[k][c] * h[k]
  // second column's OOB reads land in pw2T's 2MB padding (never written back) -> safe.
  {
    float a0[4] = {0.f,0.f,0.f,0.f};
    float a1[4] = {0.f,0.f,0.f,0.f};
    const int c2 = 512 + t;
    for (int k = 0; k < D_; k += 4){
      #pragma unroll
      for (int j = 0; j < 4; ++j){
        const float hv = vb_[k+j];
        const float* rowp = pw2T + (size_t)(k+j)*NC_;
        a0[j] += rowp[t]  * hv;
        a1[j] += rowp[c2] * hv;
      }
    }
    out[(size_t)b*NC_ + t] = ((a0[0]+a0[1])+(a0[2]+a0[3])) + pb2[t];
    if (c2 < NC_)
      out[(size_t)b*NC_ + c2] = ((a1[0]+a1[1])+(a1[2]+a1[3])) + pb2[c2];
  }
}

extern "C" void kernel_launch(void* const* d_in, const int* in_sizes, int n_in,
                              void* d_out, int out_size, void* d_ws, size_t ws_size,
                              hipStream_t stream) {
  (void)in_sizes; (void)n_in; (void)out_size; (void)ws_size;
  const float* x_items  = (const float*)d_in[0];
  const float* x_query  = (const float*)d_in[1];
  const float* psi_x_w1 = (const float*)d_in[2];
  const float* psi_x_b1 = (const float*)d_in[3];
  const float* psi_x_w2 = (const float*)d_in[4];
  const float* psi_x_b2 = (const float*)d_in[5];
  const float* psi_q_w1 = (const float*)d_in[6];
  const float* psi_q_b1 = (const float*)d_in[7];
  const float* psi_q_w2 = (const float*)d_in[8];
  const float* psi_q_b2 = (const float*)d_in[9];
  const float* q_w      = (const float*)d_in[10];
  const float* q_b      = (const float*)d_in[11];
  const float* k_w      = (const float*)d_in[12];
  // k_b (d_in[13]) unused: constant score shift cancels in softmax
  const float* v_w      = (const float*)d_in[14];
  const float* v_b      = (const float*)d_in[15];
  const float* phi_w1   = (const float*)d_in[16];
  const float* phi_b1   = (const float*)d_in[17];
  const float* phi_w2   = (const float*)d_in[18];
  const float* phi_b2   = (const float*)d_in[19];
  float* out = (float*)d_out;

  char* ws = (char*)d_ws;
  unsigned short* w1p = (unsigned short*)(ws);                 // 131072
  float* qkw2 = (float*)(ws + 131072);                         // 65536
  float* part = (float*)(ws + 196608);                         // 4194304
  float* esum = (float*)(ws + 4390912);                        // 8192
  float* w2T  = (float*)(ws + 4399104);                        // 1048576
  float* vwT  = (float*)(ws + 5447680);                        // 1048576
  float* pw1T = (float*)(ws + 6496256);                        // 1048576
  float* w2qT = (float*)(ws + 7544832);                        // 1048576
  float* qwT  = (float*)(ws + 8593408);                        // 1048576
  float* pw2T = (float*)(ws + 9641984);                        // 2097152 (2048000 used + pad)
  // total ws usage: 11,739,136 B

  hipLaunchKernelGGL(k_prep2, dim3(576), dim3(512), 0, stream,
                     psi_x_w1, w1p,
                     psi_x_w2, w2T, v_w, vwT, phi_w1, pw1T,
                     psi_q_w2, w2qT, q_w, qwT, phi_w2, pw2T);
  hipLaunchKernelGGL(k_q, dim3(32), dim3(512), 0, stream,
                     x_query, psi_q_w1, psi_q_b1, w2qT, psi_q_b2,
                     qwT, q_b, k_w, psi_x_w2, qkw2);
  hipLaunchKernelGGL(k_main, dim3(NT_, B_), dim3(512), 0, stream,
                     x_items, w1p, psi_x_b1, qkw2, part, esum);
  hipLaunchKernelGGL(k_tail3, dim3(32), dim3(512), 0, stream,
                     part, esum, w2T, psi_x_b2, vwT, v_b,
                     pw1T, phi_b1, pw2T, phi_b2, out);
}

// Round 8
// 358.504 us; speedup vs baseline: 1.8367x; 1.2769x over previous
//
#include <hip/hip_runtime.h>
#include <hip/hip_bf16.h>

#define B_ 32
#define N_ 8192
#define DI_ 128
#define D_ 512
#define NC_ 1000
#define TN_ 128          // items per output tile (per block)
#define SN_ 32           // items per sub-tile
#define NSUB_ 4          // sub-tiles per block
#define NT_ 64           // tiles = N_/TN_
#define XROW_ 136        // x_lds row stride in shorts (pad +8)

typedef short s8v __attribute__((ext_vector_type(8)));
typedef float f4v __attribute__((ext_vector_type(4)));

__device__ __forceinline__ unsigned short f2bf(float f){
  union { float f; unsigned u; } c; c.f = f;
  unsigned r = c.u + 0x7fffu + ((c.u >> 16) & 1u);
  return (unsigned short)(r >> 16);
}

// hardware v_cvt_pk_bf16_f32: 2 floats -> packed bf16 (RNE), a in low 16
__device__ __forceinline__ unsigned pk2bf(float a, float b){
  float2 f; f.x = a; f.y = b;
  __hip_bfloat162 h = __float22bfloat162_rn(f);
  union { __hip_bfloat162 h; unsigned u; } c; c.h = h;
  return c.u;
}

// exact GELU: 0.5x(1+erf(x/sqrt2)); Abramowitz-Stegun 7.1.26, |err| <= 1.5e-7
__device__ __forceinline__ float gelu_f(float x){
  float ax = fabsf(x) * 0.70710678118654752f;
  float t = __builtin_amdgcn_rcpf(1.0f + 0.3275911f * ax);
  float poly = ((((1.061405429f*t - 1.453152027f)*t + 1.421413741f)*t
                 - 0.284496736f)*t + 0.254829592f)*t;
  float e = __expf(-ax*ax);
  float erf_ax = 1.0f - poly*e;
  erf_ax = (x >= 0.0f) ? erf_ax : -erf_ax;
  return 0.5f * x * (1.0f + erf_ax);
}

__device__ __forceinline__ float wsum64(float v){
  #pragma unroll
  for (int off = 32; off; off >>= 1) v += __shfl_xor(v, off, 64);
  return v;
}

// ---------------- prep: w1 bf16 pack + transpose 6 tail/query weight matrices ----------------
// (FROZEN from r5.) Row-per-thread GEMVs have 2KB-stride lane access; transposing once makes
// every GEMV stage lane-coalesced.
__global__ __launch_bounds__(512)
void k_prep2(const float* __restrict__ w1, unsigned short* __restrict__ w1p,
             const float* __restrict__ sw0, float* __restrict__ dt0,   // psi_x_w2 -> w2T
             const float* __restrict__ sw1, float* __restrict__ dt1,   // v_w     -> vwT
             const float* __restrict__ sw2, float* __restrict__ dt2,   // phi_w1  -> pw1T
             const float* __restrict__ sw3, float* __restrict__ dt3,   // psi_q_w2-> w2qT
             const float* __restrict__ sw4, float* __restrict__ dt4,   // q_w     -> qwT
             const float* __restrict__ pw2, float* __restrict__ pw2T){
  const int t = threadIdx.x;
  const int bid = blockIdx.x;
  if (bid < 128){
    const int i = bid*512 + t;                 // < 65536 = D_*DI_
    const int j = i / DI_, kc = i % DI_;
    const int kk = kc >> 5, q = (kc >> 3) & 3, s = kc & 7;
    w1p[((kk*D_ + j)*4 + q)*8 + s] = f2bf(w1[i]);
    return;
  }
  __shared__ float tile[64][65];               // +1 pad: 2-way LDS aliasing only (free)
  const int r0 = t >> 6;                       // 0..7
  const int c  = t & 63;
  if (bid < 448){
    const int id = bid - 128;
    const int mi = id >> 6;                    // matrix 0..4
    const int tt = id & 63;
    const int to = tt >> 3, tk = tt & 7;       // row-tile (out), col-tile (in)
    const float* src = mi==0?sw0: mi==1?sw1: mi==2?sw2: mi==3?sw3: sw4;
    float*       dst = mi==0?dt0: mi==1?dt1: mi==2?dt2: mi==3?dt3: dt4;
    #pragma unroll
    for (int i = 0; i < 8; ++i){
      const int r = r0 + i*8;
      tile[r][c] = src[(size_t)(to*64 + r)*D_ + tk*64 + c];
    }
    __syncthreads();
    #pragma unroll
    for (int i = 0; i < 8; ++i){
      const int r = r0 + i*8;
      dst[(size_t)(tk*64 + r)*D_ + to*64 + c] = tile[c][r];
    }
  } else {
    const int id = bid - 448;                  // 0..127
    const int tr = id >> 3, tk = id & 7;       // tr: 1000-row tiles (16), tk: 512-col tiles (8)
    #pragma unroll
    for (int i = 0; i < 8; ++i){
      const int r = r0 + i*8;
      const int ro = tr*64 + r;
      tile[r][c] = (ro < NC_) ? pw2[(size_t)ro*D_ + tk*64 + c] : 0.f;
    }
    __syncthreads();
    #pragma unroll
    for (int i = 0; i < 8; ++i){
      const int r = r0 + i*8;
      const int co = tr*64 + c;
      if (co < NC_)
        pw2T[(size_t)(tk*64 + r)*NC_ + co] = tile[c][r];
    }
  }
}

// ---------------- generic wide batched GEMV stage (compile-time J/ACT/HASB) ----------------
// Y[b][j] = act(scale * sum_k WT[k][j] * X[b][k] + bias[j])
// grid (J/64 rounded up, 32) x 512: each block reads ONLY a 64-col weight slice (128 KB).
// r5 lesson: per-CU streaming BW is ~25-50 GB/s; one block per batch reading 4-5 MB
// is ~100 us/kernel. 256 blocks x 128 KB each makes per-block time ~3 us; the 32x
// weight re-read (32 MB aggregate) rides the ~34 TB/s aggregate L2, which is abundant.
// r7->r8 hardening: J is a template param (no runtime-J) and HASB=false stages never
// receive or touch a null bias pointer.
template<int J, bool ACT, bool HASB>
__global__ __launch_bounds__(512)
void k_gemv(const float* __restrict__ WT, const float* __restrict__ X,
            const float* __restrict__ bias, float* __restrict__ Y,
            const float scale){
  const int sl = blockIdx.x, b = blockIdx.y, t = threadIdx.x;
  const int c = t & 63, w = t >> 6;
  __shared__ float xs[D_];
  __shared__ float red[8][64];
  xs[t] = X[(size_t)b*D_ + t];
  __syncthreads();
  const int j = sl*64 + c;
  const float* wp = WT + (size_t)(w*64)*J + j;
  const float* xp = xs + w*64;
  float a0=0.f, a1=0.f, a2=0.f, a3=0.f;
  #pragma unroll
  for (int k = 0; k < 64; k += 4){
    a0 += wp[(size_t)(k+0)*J] * xp[k+0];
    a1 += wp[(size_t)(k+1)*J] * xp[k+1];
    a2 += wp[(size_t)(k+2)*J] * xp[k+2];
    a3 += wp[(size_t)(k+3)*J] * xp[k+3];
  }
  red[w][c] = (a0+a1)+(a2+a3);
  __syncthreads();
  if (w == 0 && j < J){
    float s = ((red[0][c]+red[1][c])+(red[2][c]+red[3][c]))
            + ((red[4][c]+red[5][c])+(red[6][c]+red[7][c]));
    s = s * scale;
    if (HASB) s += bias[j];
    Y[(size_t)b*J + j] = ACT ? gelu_f(s) : s;
  }
}

// stage 1 of query chain: X built on the fly: xs[k] = gelu(xq[b]*w1q[k]+b1q[k])
__global__ __launch_bounds__(512)
void k_gemv_q1(const float* __restrict__ xq,  const float* __restrict__ w1q,
               const float* __restrict__ b1q,
               const float* __restrict__ WT,  const float* __restrict__ bias,
               float* __restrict__ Y){
  const int sl = blockIdx.x, b = blockIdx.y, t = threadIdx.x;
  const int c = t & 63, w = t >> 6;
  __shared__ float xs[D_];
  __shared__ float red[8][64];
  xs[t] = gelu_f(xq[b] * w1q[t] + b1q[t]);
  __syncthreads();
  const int j = sl*64 + c;
  const float* wp = WT + (size_t)(w*64)*D_ + j;
  const float* xp = xs + w*64;
  float a0=0.f, a1=0.f, a2=0.f, a3=0.f;
  #pragma unroll
  for (int k = 0; k < 64; k += 4){
    a0 += wp[(size_t)(k+0)*D_] * xp[k+0];
    a1 += wp[(size_t)(k+1)*D_] * xp[k+1];
    a2 += wp[(size_t)(k+2)*D_] * xp[k+2];
    a3 += wp[(size_t)(k+3)*D_] * xp[k+3];
  }
  red[w][c] = (a0+a1)+(a2+a3);
  __syncthreads();
  if (w == 0){
    float s = ((red[0][c]+red[1][c])+(red[2][c]+red[3][c]))
            + ((red[4][c]+red[5][c])+(red[6][c]+red[7][c]));
    Y[(size_t)b*D_ + j] = s + bias[j];
  }
}

// ---------------- main: GEMM1 + gelu + score(qkw2.h1) + weighted hbar accumulate ----------------
// GEMM2 eliminated algebraically: u = W2 @ (sum e*h1)/sum(e) + b2, applied per batch in tail.
// launch_bounds(512,2): 256-reg cap; natural allocation ~156 total regs -> no spill. (FROZEN from r3.)
__global__ __launch_bounds__(512, 2)
void k_main(const float* __restrict__ x,                 // [B,N,DI]
            const unsigned short* __restrict__ w1p,      // packed bf16
            const float* __restrict__ b1,
            const float* __restrict__ qkw2,              // [B,D]
            float* __restrict__ part,                    // [B,NT,D] : sum e*h1 partials
            float* __restrict__ esum){                   // [B,NT]
  const int tile = blockIdx.x;       // 0..63
  const int b = blockIdx.y;          // 0..31
  const int t = threadIdx.x;         // 0..511
  const int lane = t & 63;
  const int wid = t >> 6;            // 0..7
  const int ln = lane & 15;
  const int q  = lane >> 4;          // 0..3

  __shared__ unsigned short x_lds[2][SN_ * XROW_];  // 2 x 8704 B
  __shared__ float s_ws[8][SN_];                    // 1024 B
  __shared__ float e_lds[SN_];                      // 128 B
  __shared__ float sb1[D_];                         // 2048 B
  __shared__ float sq2[D_];                         // 2048 B

  const int jb = wid * 64;              // this wave's 64-col j block
  const unsigned short* w1base = w1p + (jb + ln)*32 + q*8;
  const float* xbase = x + ((size_t)b * N_ + tile * TN_) * DI_;

  // invariants to LDS + stage sub 0
  sb1[t] = b1[t];
  sq2[t] = qkw2[b*D_ + t];
  {
    const float4* x4 = (const float4*)xbase;
    #pragma unroll
    for (int i = 0; i < 2; ++i){
      const int f = i*512 + t;            // 1024 float4 per sub-tile
      float4 v = x4[f];
      const int m = f >> 5;
      const int k = (f & 31) << 2;
      uint2 pk;
      pk.x = pk2bf(v.x, v.y);
      pk.y = pk2bf(v.z, v.w);
      *(uint2*)&x_lds[0][m*XROW_ + k] = pk;
    }
  }
  __syncthreads();

  f4v zacc[4];
  #pragma unroll
  for (int i = 0; i < 4; ++i) zacc[i] = (f4v){0.f,0.f,0.f,0.f};
  float etot = 0.f;

  for (int s = 0; s < NSUB_; ++s){
    const unsigned short* xb = x_lds[s & 1];

    f4v acc[8];
    #pragma unroll
    for (int i = 0; i < 8; ++i) acc[i] = (f4v){0.f,0.f,0.f,0.f};

    // ---- GEMM1: h1^T[j,m] = sum_k w1[j,k] * x[m,k] ----
    #pragma unroll
    for (int kk = 0; kk < 4; ++kk){
      const int k = kk*32 + q*8;
      s8v aw[4];
      #pragma unroll
      for (int jt = 0; jt < 4; ++jt)
        aw[jt] = *(const s8v*)(w1base + kk*(D_*32) + jt*(16*32));
      s8v bx[2];
      #pragma unroll
      for (int mi = 0; mi < 2; ++mi)
        bx[mi] = *(const s8v*)&xb[(mi*16 + ln)*XROW_ + k];
      #pragma unroll
      for (int jt = 0; jt < 4; ++jt)
        #pragma unroll
        for (int mi = 0; mi < 2; ++mi)
          acc[jt*2+mi] = __builtin_amdgcn_mfma_f32_16x16x32_bf16(aw[jt], bx[mi], acc[jt*2+mi], 0,0,0);
    }

    // ---- prefetch next sub-tile into regs (HBM latency hides under gelu/score) ----
    float4 pv0, pv1;
    if (s + 1 < NSUB_){
      const float4* x4 = (const float4*)(xbase + (size_t)(s+1)*SN_*DI_);
      pv0 = x4[t];
      pv1 = x4[512 + t];
    }

    // ---- bias + exact GELU (in place) + score partial over this wave's 64 j ----
    float sp0 = 0.f, sp1 = 0.f;
    #pragma unroll
    for (int jt = 0; jt < 4; ++jt){
      const f4v bv = *(const f4v*)&sb1[jb + jt*16 + q*4];
      const f4v qv = *(const f4v*)&sq2[jb + jt*16 + q*4];
      #pragma unroll
      for (int mi = 0; mi < 2; ++mi){
        f4v a = acc[jt*2+mi];
        a[0] = gelu_f(a[0] + bv[0]);
        a[1] = gelu_f(a[1] + bv[1]);
        a[2] = gelu_f(a[2] + bv[2]);
        a[3] = gelu_f(a[3] + bv[3]);
        acc[jt*2+mi] = a;
        const float d = qv[0]*a[0] + qv[1]*a[1] + qv[2]*a[2] + qv[3]*a[3];
        if (mi == 0) sp0 += d; else sp1 += d;
      }
    }
    // reduce over q lanes (xor 16,32): full-j partial per m = mi*16+ln
    sp0 += __shfl_xor(sp0, 16, 64); sp0 += __shfl_xor(sp0, 32, 64);
    sp1 += __shfl_xor(sp1, 16, 64); sp1 += __shfl_xor(sp1, 32, 64);
    if (q == 0) s_ws[wid][lane] = sp0;        // lane = ln      -> m = ln
    if (q == 1) s_ws[wid][lane] = sp1;        // lane = 16+ln   -> m = 16+ln

    // ---- write prefetched x to the other LDS buffer ----
    if (s + 1 < NSUB_){
      unsigned short* xn = &x_lds[(s+1) & 1][0];
      int f = t, m = f >> 5, k = (f & 31) << 2;
      uint2 pk;
      pk.x = pk2bf(pv0.x, pv0.y);
      pk.y = pk2bf(pv0.z, pv0.w);
      *(uint2*)&xn[m*XROW_ + k] = pk;
      f = 512 + t; m = f >> 5; k = (f & 31) << 2;
      pk.x = pk2bf(pv1.x, pv1.y);
      pk.y = pk2bf(pv1.z, pv1.w);
      *(uint2*)&xn[m*XROW_ + k] = pk;
    }
    __syncthreads();     // (A) scores complete, staging complete

    if (t < SN_){
      float sc = 0.f;
      #pragma unroll
      for (int w = 0; w < 8; ++w) sc += s_ws[w][t];
      e_lds[t] = __expf(sc);     // constant shift (qk.b2, k_b) cancels in softmax
    }
    __syncthreads();     // (B) e ready

    if (wid == 0){
      float v = (lane < SN_) ? e_lds[lane] : 0.f;
      etot += wsum64(v);
    }

    // ---- weighted hbar accumulate: zacc[j] += sum_m e[m]*h1[m,j] (per-lane mi part) ----
    {
      const float em0 = e_lds[ln];
      const float em1 = e_lds[16 + ln];
      #pragma unroll
      for (int jt = 0; jt < 4; ++jt){
        const f4v a0 = acc[jt*2+0];
        const f4v a1 = acc[jt*2+1];
        #pragma unroll
        for (int r = 0; r < 4; ++r)
          zacc[jt][r] += em0*a0[r] + em1*a1[r];
      }
    }
    // no barrier needed: next iter's e_lds write is after its own barrier (A)
  }

  if (t == 0) esum[b*NT_ + tile] = etot;

  // reduce zacc over ln lanes (same q => same j set), write 4x float4 per q-lane
  #pragma unroll
  for (int jt = 0; jt < 4; ++jt){
    #pragma unroll
    for (int r = 0; r < 4; ++r){
      float v = zacc[jt][r];
      v += __shfl_xor(v, 1, 64);
      v += __shfl_xor(v, 2, 64);
      v += __shfl_xor(v, 4, 64);
      v += __shfl_xor(v, 8, 64);
      zacc[jt][r] = v;
    }
    if (ln == 0){
      float4 o; o.x = zacc[jt][0]; o.y = zacc[jt][1]; o.z = zacc[jt][2]; o.w = zacc[jt][3];
      *(float4*)&part[((size_t)(b*NT_ + tile))*D_ + jb + jt*16 + q*4] = o;
    }
  }
}

// u[b][col] = (1/sum e) * sum_tl part[b][tl][col];  grid (32,4) x 128  (wide: 128 blocks)
__global__ __launch_bounds__(128)
void k_fu(const float* __restrict__ part, const float* __restrict__ esum,
          float* __restrict__ u){
  const int b = blockIdx.x, sl = blockIdx.y, t = threadIdx.x;
  float p = esum[b*NT_ + (t & 63)];
  p = wsum64(p);
  const float linv = 1.0f / p;
  const int col = sl*128 + t;
  const float* pb = part + (size_t)b*NT_*D_ + col;
  float s = 0.f;
  #pragma unroll 8
  for (int tl = 0; tl < NT_; ++tl) s += pb[tl*D_];
  u[b*D_ + col] = s * linv;
}

extern "C" void kernel_launch(void* const* d_in, const int* in_sizes, int n_in,
                              void* d_out, int out_size, void* d_ws, size_t ws_size,
                              hipStream_t stream) {
  (void)in_sizes; (void)n_in; (void)out_size; (void)ws_size;
  const float* x_items  = (const float*)d_in[0];
  const float* x_query  = (const float*)d_in[1];
  const float* psi_x_w1 = (const float*)d_in[2];
  const float* psi_x_b1 = (const float*)d_in[3];
  const float* psi_x_w2 = (const float*)d_in[4];
  const float* psi_x_b2 = (const float*)d_in[5];
  const float* psi_q_w1 = (const float*)d_in[6];
  const float* psi_q_b1 = (const float*)d_in[7];
  const float* psi_q_w2 = (const float*)d_in[8];
  const float* psi_q_b2 = (const float*)d_in[9];
  const float* q_w      = (const float*)d_in[10];
  const float* q_b      = (const float*)d_in[11];
  const float* k_w      = (const float*)d_in[12];
  // k_b (d_in[13]) unused: constant score shift cancels in softmax
  const float* v_w      = (const float*)d_in[14];
  const float* v_b      = (const float*)d_in[15];
  const float* phi_w1   = (const float*)d_in[16];
  const float* phi_b1   = (const float*)d_in[17];
  const float* phi_w2   = (const float*)d_in[18];
  const float* phi_b2   = (const float*)d_in[19];
  float* out = (float*)d_out;

  // Workspace layout: max offset+size = 11,739,136 B (round 5's proven-safe footprint).
  // Aliases (all safe by serial stream ordering within one iteration):
  //  - h2g/qvg/qkg live in part[0..192KB): consumed by query chain BEFORE k_main writes part.
  //  - ub/u2b/zb/hb live in w2qT's 1MB: w2qT only read by query stages, all BEFORE k_fu.
  char* ws = (char*)d_ws;
  unsigned short* w1p = (unsigned short*)(ws);                 // 131072
  float* qkw2 = (float*)(ws + 131072);                         // 65536
  float* part = (float*)(ws + 196608);                         // 4194304
  float* h2g  = (float*)(ws + 196608);                         // 65536  (alias: part)
  float* qvg  = (float*)(ws + 262144);                         // 65536  (alias: part)
  float* qkg  = (float*)(ws + 327680);                         // 65536  (alias: part)
  float* esum = (float*)(ws + 4390912);                        // 8192
  float* w2T  = (float*)(ws + 4399104);                        // 1048576
  float* vwT  = (float*)(ws + 5447680);                        // 1048576
  float* pw1T = (float*)(ws + 6496256);                        // 1048576
  float* w2qT = (float*)(ws + 7544832);                        // 1048576
  float* ub   = (float*)(ws + 7544832);                        // 65536  (alias: w2qT)
  float* u2b  = (float*)(ws + 7610368);                        // 65536  (alias: w2qT)
  float* zb   = (float*)(ws + 7675904);                        // 65536  (alias: w2qT)
  float* hb   = (float*)(ws + 7741440);                        // 65536  (alias: w2qT)
  float* qwT  = (float*)(ws + 8593408);                        // 1048576
  float* pw2T = (float*)(ws + 9641984);                        // 2097152 (2048000 used + pad)
  // total ws usage: 11,739,136 B (== round-5 proven footprint)

  const float SC = 0.04419417382415922f;   // 512^-0.5

  hipLaunchKernelGGL(k_prep2, dim3(576), dim3(512), 0, stream,
                     psi_x_w1, w1p,
                     psi_x_w2, w2T, v_w, vwT, phi_w1, pw1T,
                     psi_q_w2, w2qT, q_w, qwT, phi_w2, pw2T);
  // query chain: 4 wide stages (256 blocks each)
  hipLaunchKernelGGL(k_gemv_q1, dim3(8, 32), dim3(512), 0, stream,
                     x_query, psi_q_w1, psi_q_b1, w2qT, psi_q_b2, h2g);
  hipLaunchKernelGGL(HIP_KERNEL_NAME(k_gemv<D_, false, true>), dim3(8, 32), dim3(512), 0, stream,
                     qwT, h2g, q_b, qvg, 1.0f);
  hipLaunchKernelGGL(HIP_KERNEL_NAME(k_gemv<D_, false, false>), dim3(8, 32), dim3(512), 0, stream,
                     k_w, qvg, q_b /*unused*/, qkg, SC);             // qk[d] = sc*sum_i kw[i][d] qv[i]
  hipLaunchKernelGGL(HIP_KERNEL_NAME(k_gemv<D_, false, false>), dim3(8, 32), dim3(512), 0, stream,
                     psi_x_w2, qkg, q_b /*unused*/, qkw2, 1.0f);     // qkw2[k] = sum_j qk[j] w2[j][k]
  hipLaunchKernelGGL(k_main, dim3(NT_, B_), dim3(512), 0, stream,
                     x_items, w1p, psi_x_b1, qkw2, part, esum);
  // tail: u-reduce + 4 wide stages
  hipLaunchKernelGGL(k_fu, dim3(32, 4), dim3(128), 0, stream,
                     part, esum, ub);
  hipLaunchKernelGGL(HIP_KERNEL_NAME(k_gemv<D_, false, true>), dim3(8, 32), dim3(512), 0, stream,
                     w2T, ub, psi_x_b2, u2b, 1.0f);
  hipLaunchKernelGGL(HIP_KERNEL_NAME(k_gemv<D_, false, true>), dim3(8, 32), dim3(512), 0, stream,
                     vwT, u2b, v_b, zb, 1.0f);
  hipLaunchKernelGGL(HIP_KERNEL_NAME(k_gemv<D_, true, true>), dim3(8, 32), dim3(512), 0, stream,
                     pw1T, zb, phi_b1, hb, 1.0f);                    // gelu epilogue
  hipLaunchKernelGGL(HIP_KERNEL_NAME(k_gemv<NC_, false, true>), dim3(16, 32), dim3(512), 0, stream,
                     pw2T, hb, phi_b2, out, 1.0f);
}